// Round 1
// baseline (1141.947 us; speedup 1.0000x reference)
//
#include <hip/hip_runtime.h>

constexpr int HID = 64;

__global__ void k_init(int* __restrict__ cnt, int n, float* __restrict__ out, int d) {
  int i = blockIdx.x * blockDim.x + threadIdx.x;
  if (i < n) cnt[i] = 0;
  if (i < d) out[i] = 0.f;
}

__global__ void k_count(const int* __restrict__ dst, int E, int* __restrict__ cnt) {
  int e = blockIdx.x * blockDim.x + threadIdx.x;
  if (e < E) atomicAdd(&cnt[dst[e]], 1);
}

__global__ __launch_bounds__(1024)
void k_scan(const int* __restrict__ cnt, int N,
            int* __restrict__ row_start, int* __restrict__ cursor,
            float* __restrict__ dinv) {
  __shared__ int part[1024];
  int t = threadIdx.x;
  int C = (N + 1023) >> 10;
  int lo = t * C;
  int hi = min(lo + C, N);
  int s = 0;
  for (int i = lo; i < hi; ++i) s += cnt[i];
  part[t] = s;
  __syncthreads();
  for (int off = 1; off < 1024; off <<= 1) {
    int v = (t >= off) ? part[t - off] : 0;
    __syncthreads();
    part[t] += v;
    __syncthreads();
  }
  int run = (t == 0) ? 0 : part[t - 1];
  for (int i = lo; i < hi; ++i) {
    int c = cnt[i];
    row_start[i] = run;
    cursor[i] = run;
    dinv[i] = rsqrtf((float)(c + 1));
    run += c;
  }
  if (t == 0) row_start[N] = part[1023];
}

__global__ void k_fill(const int* __restrict__ src, const int* __restrict__ dst, int E,
                       int* __restrict__ cursor, int* __restrict__ csr_src) {
  int e = blockIdx.x * blockDim.x + threadIdx.x;
  if (e < E) {
    int d = dst[e];
    int pos = atomicAdd(&cursor[d], 1);
    csr_src[pos] = src[e];
  }
}

// hs[row, j] = (sum_k x[row,k] * W[k,j]) * dinv[row]
template<int DIN>
__global__ void k_mm_in(const float* __restrict__ xin, const float* __restrict__ W,
                        const float* __restrict__ dinv, float* __restrict__ hs, int N) {
  __shared__ float Wl[DIN * HID];
  int t = threadIdx.x;
  for (int i = t; i < DIN * HID; i += 256) Wl[i] = W[i];
  __syncthreads();
  int row = blockIdx.x * 4 + (t >> 6);
  int j = t & 63;
  if (row >= N) return;
  const float* xr = xin + row * DIN;
  float acc = 0.f;
  #pragma unroll
  for (int k = 0; k < DIN; ++k) acc += xr[k] * Wl[k * HID + j];
  hs[row * HID + j] = acc * dinv[row];
}

// agg[d, j] = hs[d, j] + sum_{s in in(d)} hs[s, j]   (one wave per node, lane = feature)
__global__ void k_aggregate(const float* __restrict__ hs, const int* __restrict__ row_start,
                            const int* __restrict__ csr_src, float* __restrict__ agg, int N) {
  int w = (blockIdx.x * blockDim.x + threadIdx.x) >> 6;
  int j = threadIdx.x & 63;
  if (w >= N) return;
  int e = row_start[w];
  int s1 = row_start[w + 1];
  float acc = hs[w * HID + j];  // self loop: hs[d]*dinv[d], final *dinv[d] applied in k_post
  for (; e + 1 < s1; e += 2) {
    int sa = csr_src[e];
    int sb = csr_src[e + 1];
    acc += hs[sa * HID + j];
    acc += hs[sb * HID + j];
  }
  if (e < s1) acc += hs[csr_src[e] * HID + j];
  agg[w * HID + j] = acc;
}

// v = relu(agg*dinv + b); LN(v)*g+be; out = relu(v @ L + lb)
template<int DOUT>
__global__ void k_post(const float* __restrict__ agg, const float* __restrict__ dinv,
                       const float* __restrict__ b, const float* __restrict__ g,
                       const float* __restrict__ be, const float* __restrict__ L,
                       const float* __restrict__ lb, float* __restrict__ xout, int N) {
  __shared__ float Ll[HID * DOUT];
  __shared__ float lbl[DOUT];
  __shared__ float bl[HID], gl[HID], bel[HID];
  __shared__ float vall[4 * HID];
  int t = threadIdx.x;
  for (int i = t; i < HID * DOUT; i += 256) Ll[i] = L[i];
  if (t < HID) { bl[t] = b[t]; gl[t] = g[t]; bel[t] = be[t]; }
  if (t < DOUT) lbl[t] = lb[t];
  __syncthreads();
  int w = t >> 6, j = t & 63;
  int row = blockIdx.x * 4 + w;
  if (row >= N) return;
  float v = agg[row * HID + j] * dinv[row] + bl[j];
  v = fmaxf(v, 0.f);
  float s = v;
  #pragma unroll
  for (int m = 1; m < 64; m <<= 1) s += __shfl_xor(s, m);
  float mu = s * (1.f / 64.f);
  float d = v - mu;
  float q = d * d;
  #pragma unroll
  for (int m = 1; m < 64; m <<= 1) q += __shfl_xor(q, m);
  float inv = rsqrtf(q * (1.f / 64.f) + 1e-5f);
  float nv = d * inv * gl[j] + bel[j];
  vall[w * 64 + j] = nv;  // wave-local segment: no barrier needed (same-wave RAW, compiler waits lgkmcnt)
  if (j < DOUT) {
    float o = lbl[j];
    #pragma unroll
    for (int k = 0; k < HID; ++k) o += vall[w * 64 + k] * Ll[k * DOUT + j];
    o = fmaxf(o, 0.f);
    xout[row * DOUT + j] = o;
  }
}

// column max over [N, D]; values are post-relu (>=0) so int-compare atomicMax is order-correct
__global__ void k_colmax(const float* __restrict__ x, int N, int D, float* __restrict__ out) {
  int j = threadIdx.x;
  if (j >= D) return;
  float m = 0.f;
  for (int r = blockIdx.x; r < N; r += gridDim.x) m = fmaxf(m, x[r * D + j]);
  atomicMax((int*)&out[j], __float_as_int(m));
}

extern "C" void kernel_launch(void* const* d_in, const int* in_sizes, int n_in,
                              void* d_out, int out_size, void* d_ws, size_t ws_size,
                              hipStream_t stream) {
  const float* x = (const float*)d_in[0];
  const int* ei = (const int*)d_in[1];
  int N = in_sizes[0] / 6;
  int E = in_sizes[1] / 2;
  const int* src = ei;
  const int* dst = ei + E;

  const float *W[3], *b[3], *g[3], *be[3], *L[3], *lb[3];
  for (int l = 0; l < 3; ++l) {
    W[l]  = (const float*)d_in[2 + 6 * l + 0];
    b[l]  = (const float*)d_in[2 + 6 * l + 1];
    g[l]  = (const float*)d_in[2 + 6 * l + 2];
    be[l] = (const float*)d_in[2 + 6 * l + 3];
    L[l]  = (const float*)d_in[2 + 6 * l + 4];
    lb[l] = (const float*)d_in[2 + 6 * l + 5];
  }

  char* p = (char*)d_ws;
  auto alloc = [&](size_t bytes) {
    char* r = p;
    p += (bytes + 255) & ~size_t(255);
    return r;
  };
  int* cnt       = (int*)alloc(sizeof(int) * N);
  int* row_start = (int*)alloc(sizeof(int) * (size_t)(N + 1));
  int* cursor    = (int*)alloc(sizeof(int) * N);
  int* csr_src   = (int*)alloc(sizeof(int) * E);
  float* dinv    = (float*)alloc(sizeof(float) * N);
  float* bufA    = (float*)alloc(sizeof(float) * (size_t)N * HID);
  float* bufB    = (float*)alloc(sizeof(float) * (size_t)N * HID);
  float* out1    = (float*)alloc(sizeof(float) * (size_t)N * 12);
  float* out2    = (float*)alloc(sizeof(float) * (size_t)N * 24);
  float* out3    = bufA;  // layer-3 k_post doesn't read bufA; safe reuse

  float* dout = (float*)d_out;

  const int tpb = 256;
  k_init<<<(N + tpb - 1) / tpb, tpb, 0, stream>>>(cnt, N, dout, out_size);
  k_count<<<(E + tpb - 1) / tpb, tpb, 0, stream>>>(dst, E, cnt);
  k_scan<<<1, 1024, 0, stream>>>(cnt, N, row_start, cursor, dinv);
  k_fill<<<(E + tpb - 1) / tpb, tpb, 0, stream>>>(src, dst, E, cursor, csr_src);

  int rb = (N + 3) / 4;  // 4 rows (waves) per 256-thread block

  // layer 1: x[N,6] -> out1[N,12]
  k_mm_in<6><<<rb, 256, 0, stream>>>(x, W[0], dinv, bufA, N);
  k_aggregate<<<rb, 256, 0, stream>>>(bufA, row_start, csr_src, bufB, N);
  k_post<12><<<rb, 256, 0, stream>>>(bufB, dinv, b[0], g[0], be[0], L[0], lb[0], out1, N);

  // layer 2: out1[N,12] -> out2[N,24]
  k_mm_in<12><<<rb, 256, 0, stream>>>(out1, W[1], dinv, bufA, N);
  k_aggregate<<<rb, 256, 0, stream>>>(bufA, row_start, csr_src, bufB, N);
  k_post<24><<<rb, 256, 0, stream>>>(bufB, dinv, b[1], g[1], be[1], L[1], lb[1], out2, N);

  // layer 3: out2[N,24] -> out3[N,48]
  k_mm_in<24><<<rb, 256, 0, stream>>>(out2, W[2], dinv, bufA, N);
  k_aggregate<<<rb, 256, 0, stream>>>(bufA, row_start, csr_src, bufB, N);
  k_post<48><<<rb, 256, 0, stream>>>(bufB, dinv, b[2], g[2], be[2], L[2], lb[2], out3, N);

  k_colmax<<<1024, 64, 0, stream>>>(out3, N, 48, dout);
}

// Round 2
// 861.684 us; speedup vs baseline: 1.3253x; 1.3253x over previous
//
#include <hip/hip_runtime.h>

constexpr int HID = 64;
constexpr int SCAN_B = 1024;  // elements per scan1 block

__global__ void k_init(int* __restrict__ cnt, int n, float* __restrict__ out, int d) {
  int i = blockIdx.x * blockDim.x + threadIdx.x;
  if (i < n) cnt[i] = 0;
  if (i < d) out[i] = 0.f;
}

__global__ void k_count(const int* __restrict__ dst, int E, int* __restrict__ cnt) {
  int e = blockIdx.x * blockDim.x + threadIdx.x;
  if (e < E) atomicAdd(&cnt[dst[e]], 1);
}

// Device-wide exclusive scan of cnt -> row_start, 3 stages.
// Stage 1: per-block (1024 elems) exclusive scan into row_start, block total -> blocksum.
__global__ __launch_bounds__(1024)
void k_scan1(const int* __restrict__ cnt, int N,
             int* __restrict__ row_start, int* __restrict__ blocksum) {
  __shared__ int sm[SCAN_B];
  int t = threadIdx.x;
  int i = blockIdx.x * SCAN_B + t;
  int v = (i < N) ? cnt[i] : 0;
  sm[t] = v;
  __syncthreads();
  for (int off = 1; off < SCAN_B; off <<= 1) {
    int u = (t >= off) ? sm[t - off] : 0;
    __syncthreads();
    sm[t] += u;
    __syncthreads();
  }
  if (i < N) row_start[i] = sm[t] - v;  // exclusive within block
  if (t == SCAN_B - 1) blocksum[blockIdx.x] = sm[t];
}

// Stage 2: exclusive scan of the (<=1024) block sums, in place.
__global__ __launch_bounds__(1024)
void k_scan2(int* __restrict__ blocksum, int nb) {
  __shared__ int sm[SCAN_B];
  int t = threadIdx.x;
  int v = (t < nb) ? blocksum[t] : 0;
  sm[t] = v;
  __syncthreads();
  for (int off = 1; off < SCAN_B; off <<= 1) {
    int u = (t >= off) ? sm[t - off] : 0;
    __syncthreads();
    sm[t] += u;
    __syncthreads();
  }
  if (t < nb) blocksum[t] = sm[t] - v;
}

// Stage 3: add block offsets; emit cursor + dinv. row_start[N] = E analytically.
__global__ void k_scan3(const int* __restrict__ cnt, const int* __restrict__ blocksum,
                        int N, int E, int* __restrict__ row_start,
                        int* __restrict__ cursor, float* __restrict__ dinv) {
  int i = blockIdx.x * blockDim.x + threadIdx.x;
  if (i >= N) return;
  int rs = row_start[i] + blocksum[i / SCAN_B];
  row_start[i] = rs;
  cursor[i] = rs;
  dinv[i] = rsqrtf((float)(cnt[i] + 1));
  if (i == 0) row_start[N] = E;
}

__global__ void k_fill(const int* __restrict__ src, const int* __restrict__ dst, int E,
                       int* __restrict__ cursor, int* __restrict__ csr_src) {
  int e = blockIdx.x * blockDim.x + threadIdx.x;
  if (e < E) {
    int d = dst[e];
    int pos = atomicAdd(&cursor[d], 1);
    csr_src[pos] = src[e];
  }
}

// hs[row, j] = (sum_k x[row,k] * W[k,j]) * dinv[row]
template<int DIN>
__global__ void k_mm_in(const float* __restrict__ xin, const float* __restrict__ W,
                        const float* __restrict__ dinv, float* __restrict__ hs, int N) {
  __shared__ float Wl[DIN * HID];
  int t = threadIdx.x;
  for (int i = t; i < DIN * HID; i += 256) Wl[i] = W[i];
  __syncthreads();
  int row = blockIdx.x * 4 + (t >> 6);
  int j = t & 63;
  if (row >= N) return;
  const float* xr = xin + row * DIN;
  float acc = 0.f;
  #pragma unroll
  for (int k = 0; k < DIN; ++k) acc += xr[k] * Wl[k * HID + j];
  hs[row * HID + j] = acc * dinv[row];
}

// agg[d, j] = hs[d, j] + sum_{s in in(d)} hs[s, j]   (one wave per node, lane = feature)
__global__ void k_aggregate(const float* __restrict__ hs, const int* __restrict__ row_start,
                            const int* __restrict__ csr_src, float* __restrict__ agg, int N) {
  int w = (blockIdx.x * blockDim.x + threadIdx.x) >> 6;
  int j = threadIdx.x & 63;
  if (w >= N) return;
  int e = row_start[w];
  int s1 = row_start[w + 1];
  float acc = hs[w * HID + j];  // self loop: hs[d]*dinv[d], final *dinv[d] applied in k_post
  for (; e + 1 < s1; e += 2) {
    int sa = csr_src[e];
    int sb = csr_src[e + 1];
    acc += hs[sa * HID + j];
    acc += hs[sb * HID + j];
  }
  if (e < s1) acc += hs[csr_src[e] * HID + j];
  agg[w * HID + j] = acc;
}

// v = relu(agg*dinv + b); LN(v)*g+be; out = relu(v @ L + lb)
template<int DOUT>
__global__ void k_post(const float* __restrict__ agg, const float* __restrict__ dinv,
                       const float* __restrict__ b, const float* __restrict__ g,
                       const float* __restrict__ be, const float* __restrict__ L,
                       const float* __restrict__ lb, float* __restrict__ xout, int N) {
  __shared__ float Ll[HID * DOUT];
  __shared__ float lbl[DOUT];
  __shared__ float bl[HID], gl[HID], bel[HID];
  __shared__ float vall[4 * HID];
  int t = threadIdx.x;
  for (int i = t; i < HID * DOUT; i += 256) Ll[i] = L[i];
  if (t < HID) { bl[t] = b[t]; gl[t] = g[t]; bel[t] = be[t]; }
  if (t < DOUT) lbl[t] = lb[t];
  __syncthreads();
  int w = t >> 6, j = t & 63;
  int row = blockIdx.x * 4 + w;
  if (row >= N) return;
  float v = agg[row * HID + j] * dinv[row] + bl[j];
  v = fmaxf(v, 0.f);
  float s = v;
  #pragma unroll
  for (int m = 1; m < 64; m <<= 1) s += __shfl_xor(s, m);
  float mu = s * (1.f / 64.f);
  float d = v - mu;
  float q = d * d;
  #pragma unroll
  for (int m = 1; m < 64; m <<= 1) q += __shfl_xor(q, m);
  float inv = rsqrtf(q * (1.f / 64.f) + 1e-5f);
  float nv = d * inv * gl[j] + bel[j];
  vall[w * 64 + j] = nv;  // wave-local segment: same-wave RAW, compiler inserts lgkmcnt wait
  if (j < DOUT) {
    float o = lbl[j];
    #pragma unroll
    for (int k = 0; k < HID; ++k) o += vall[w * 64 + k] * Ll[k * DOUT + j];
    o = fmaxf(o, 0.f);
    xout[row * DOUT + j] = o;
  }
}

// column max over [N, D]; values are post-relu (>=0) so int-compare atomicMax is order-correct
__global__ void k_colmax(const float* __restrict__ x, int N, int D, float* __restrict__ out) {
  int j = threadIdx.x;
  if (j >= D) return;
  float m = 0.f;
  for (int r = blockIdx.x; r < N; r += gridDim.x) m = fmaxf(m, x[r * D + j]);
  atomicMax((int*)&out[j], __float_as_int(m));
}

extern "C" void kernel_launch(void* const* d_in, const int* in_sizes, int n_in,
                              void* d_out, int out_size, void* d_ws, size_t ws_size,
                              hipStream_t stream) {
  const float* x = (const float*)d_in[0];
  const int* ei = (const int*)d_in[1];
  int N = in_sizes[0] / 6;
  int E = in_sizes[1] / 2;
  const int* src = ei;
  const int* dst = ei + E;

  const float *W[3], *b[3], *g[3], *be[3], *L[3], *lb[3];
  for (int l = 0; l < 3; ++l) {
    W[l]  = (const float*)d_in[2 + 6 * l + 0];
    b[l]  = (const float*)d_in[2 + 6 * l + 1];
    g[l]  = (const float*)d_in[2 + 6 * l + 2];
    be[l] = (const float*)d_in[2 + 6 * l + 3];
    L[l]  = (const float*)d_in[2 + 6 * l + 4];
    lb[l] = (const float*)d_in[2 + 6 * l + 5];
  }

  char* p = (char*)d_ws;
  auto alloc = [&](size_t bytes) {
    char* r = p;
    p += (bytes + 255) & ~size_t(255);
    return r;
  };
  int* cnt       = (int*)alloc(sizeof(int) * N);
  int* row_start = (int*)alloc(sizeof(int) * (size_t)(N + 1));
  int* cursor    = (int*)alloc(sizeof(int) * N);
  int* csr_src   = (int*)alloc(sizeof(int) * E);
  float* dinv    = (float*)alloc(sizeof(float) * N);
  int* blocksum  = (int*)alloc(sizeof(int) * SCAN_B);
  float* bufA    = (float*)alloc(sizeof(float) * (size_t)N * HID);
  float* bufB    = (float*)alloc(sizeof(float) * (size_t)N * HID);
  float* out1    = (float*)alloc(sizeof(float) * (size_t)N * 12);
  float* out2    = (float*)alloc(sizeof(float) * (size_t)N * 24);
  float* out3    = bufA;  // layer-3 k_post doesn't read bufA; safe reuse

  float* dout = (float*)d_out;

  const int tpb = 256;
  int nb = (N + SCAN_B - 1) / SCAN_B;
  k_init<<<(N + tpb - 1) / tpb, tpb, 0, stream>>>(cnt, N, dout, out_size);
  k_count<<<(E + tpb - 1) / tpb, tpb, 0, stream>>>(dst, E, cnt);
  k_scan1<<<nb, SCAN_B, 0, stream>>>(cnt, N, row_start, blocksum);
  k_scan2<<<1, SCAN_B, 0, stream>>>(blocksum, nb);
  k_scan3<<<(N + tpb - 1) / tpb, tpb, 0, stream>>>(cnt, blocksum, N, E, row_start, cursor, dinv);
  k_fill<<<(E + tpb - 1) / tpb, tpb, 0, stream>>>(src, dst, E, cursor, csr_src);

  int rb = (N + 3) / 4;  // 4 rows (waves) per 256-thread block

  // layer 1: x[N,6] -> out1[N,12]
  k_mm_in<6><<<rb, 256, 0, stream>>>(x, W[0], dinv, bufA, N);
  k_aggregate<<<rb, 256, 0, stream>>>(bufA, row_start, csr_src, bufB, N);
  k_post<12><<<rb, 256, 0, stream>>>(bufB, dinv, b[0], g[0], be[0], L[0], lb[0], out1, N);

  // layer 2: out1[N,12] -> out2[N,24]
  k_mm_in<12><<<rb, 256, 0, stream>>>(out1, W[1], dinv, bufA, N);
  k_aggregate<<<rb, 256, 0, stream>>>(bufA, row_start, csr_src, bufB, N);
  k_post<24><<<rb, 256, 0, stream>>>(bufB, dinv, b[1], g[1], be[1], L[1], lb[1], out2, N);

  // layer 3: out2[N,24] -> out3[N,48]
  k_mm_in<24><<<rb, 256, 0, stream>>>(out2, W[2], dinv, bufA, N);
  k_aggregate<<<rb, 256, 0, stream>>>(bufA, row_start, csr_src, bufB, N);
  k_post<48><<<rb, 256, 0, stream>>>(bufB, dinv, b[2], g[2], be[2], L[2], lb[2], out3, N);

  k_colmax<<<1024, 64, 0, stream>>>(out3, N, 48, dout);
}

// Round 3
// 746.240 us; speedup vs baseline: 1.5303x; 1.1547x over previous
//
#include <hip/hip_runtime.h>

constexpr int HID = 64;
constexpr int SCAN_B = 1024;   // elements per scan1 block
constexpr int BSHIFT = 9;      // bucket = dst >> 9  (512 nodes per bucket)
constexpr int NBMAX = 256;     // max buckets (N=100k -> 196)

__global__ void k_init(int* __restrict__ cnt, int n, float* __restrict__ out, int d) {
  int i = blockIdx.x * blockDim.x + threadIdx.x;
  if (i < n) cnt[i] = 0;
  if (i < d) out[i] = 0.f;
}

__global__ void k_count(const int* __restrict__ dst, int E, int* __restrict__ cnt) {
  int e = blockIdx.x * blockDim.x + threadIdx.x;
  if (e < E) atomicAdd(&cnt[dst[e]], 1);
}

// Device-wide exclusive scan of cnt -> row_start, 3 stages.
__global__ __launch_bounds__(1024)
void k_scan1(const int* __restrict__ cnt, int N,
             int* __restrict__ row_start, int* __restrict__ blocksum) {
  __shared__ int sm[SCAN_B];
  int t = threadIdx.x;
  int i = blockIdx.x * SCAN_B + t;
  int v = (i < N) ? cnt[i] : 0;
  sm[t] = v;
  __syncthreads();
  for (int off = 1; off < SCAN_B; off <<= 1) {
    int u = (t >= off) ? sm[t - off] : 0;
    __syncthreads();
    sm[t] += u;
    __syncthreads();
  }
  if (i < N) row_start[i] = sm[t] - v;  // exclusive within block
  if (t == SCAN_B - 1) blocksum[blockIdx.x] = sm[t];
}

__global__ __launch_bounds__(1024)
void k_scan2(int* __restrict__ blocksum, int nb) {
  __shared__ int sm[SCAN_B];
  int t = threadIdx.x;
  int v = (t < nb) ? blocksum[t] : 0;
  sm[t] = v;
  __syncthreads();
  for (int off = 1; off < SCAN_B; off <<= 1) {
    int u = (t >= off) ? sm[t - off] : 0;
    __syncthreads();
    sm[t] += u;
    __syncthreads();
  }
  if (t < nb) blocksum[t] = sm[t] - v;
}

// Stage 3: add block offsets; emit cursor + dinv + bucket cursors. row_start[N]=E.
__global__ void k_scan3(const int* __restrict__ cnt, const int* __restrict__ blocksum,
                        int N, int E, int* __restrict__ row_start,
                        int* __restrict__ cursor, float* __restrict__ dinv,
                        int* __restrict__ bucket_cur) {
  int i = blockIdx.x * blockDim.x + threadIdx.x;
  if (i >= N) return;
  int rs = row_start[i] + blocksum[i / SCAN_B];
  row_start[i] = rs;
  cursor[i] = rs;
  dinv[i] = rsqrtf((float)(cnt[i] + 1));
  if ((i & ((1 << BSHIFT) - 1)) == 0) bucket_cur[i >> BSHIFT] = rs;
  if (i == 0) row_start[N] = E;
}

// Partition edges into dst-buckets (packed src,dst) for write-local CSR fill.
constexpr int EPB = 4096;  // edges per k_part block (256 threads x 16)
__global__ __launch_bounds__(256)
void k_part(const int* __restrict__ src, const int* __restrict__ dst, int E,
            int* __restrict__ bucket_cur, uint2* __restrict__ part) {
  __shared__ int lcnt[NBMAX];
  __shared__ int lcur[NBMAX];
  int t = threadIdx.x;
  int base = blockIdx.x * EPB;
  for (int i = t; i < NBMAX; i += 256) lcnt[i] = 0;
  __syncthreads();
  #pragma unroll
  for (int i = 0; i < EPB / 256; ++i) {
    int e = base + i * 256 + t;
    if (e < E) atomicAdd(&lcnt[dst[e] >> BSHIFT], 1);
  }
  __syncthreads();
  for (int i = t; i < NBMAX; i += 256)
    lcur[i] = lcnt[i] ? atomicAdd(&bucket_cur[i], lcnt[i]) : 0;
  __syncthreads();
  #pragma unroll
  for (int i = 0; i < EPB / 256; ++i) {
    int e = base + i * 256 + t;
    if (e < E) {
      int s = src[e], d = dst[e];
      int pos = atomicAdd(&lcur[d >> BSHIFT], 1);
      part[pos] = make_uint2((unsigned)s, (unsigned)d);
    }
  }
}

// Per-bucket scatter: cursor region ~2KB, csr region ~33KB -> L2-resident.
constexpr int SPLIT = 4;
__global__ __launch_bounds__(256)
void k_fill2(const uint2* __restrict__ part, const int* __restrict__ row_start,
             int N, int* __restrict__ cursor, int* __restrict__ csr_src) {
  int b = blockIdx.x / SPLIT;
  int s = blockIdx.x % SPLIT;
  int lo_node = b << BSHIFT;
  int hi_node = min(lo_node + (1 << BSHIFT), N);
  if (lo_node >= N) return;
  int lo = row_start[lo_node];
  int hi = row_start[hi_node];
  int len = hi - lo;
  int chunk = (len + SPLIT - 1) / SPLIT;
  int clo = lo + s * chunk;
  int chi = min(clo + chunk, hi);
  for (int e = clo + threadIdx.x; e < chi; e += 256) {
    uint2 u = part[e];
    int pos = atomicAdd(&cursor[u.y], 1);
    csr_src[pos] = (int)u.x;
  }
}

// hs[row, j] = (sum_k x[row,k] * W[k,j]) * dinv[row]
template<int DIN>
__global__ void k_mm_in(const float* __restrict__ xin, const float* __restrict__ W,
                        const float* __restrict__ dinv, float* __restrict__ hs, int N) {
  __shared__ float Wl[DIN * HID];
  int t = threadIdx.x;
  for (int i = t; i < DIN * HID; i += 256) Wl[i] = W[i];
  __syncthreads();
  int row = blockIdx.x * 4 + (t >> 6);
  int j = t & 63;
  if (row >= N) return;
  const float* xr = xin + row * DIN;
  float acc = 0.f;
  #pragma unroll
  for (int k = 0; k < DIN; ++k) acc += xr[k] * Wl[k * HID + j];
  hs[row * HID + j] = acc * dinv[row];
}

// agg[d, j] = hs[d, j] + sum_{s in in(d)} hs[s, j]   (one wave per node, lane = feature)
__global__ void k_aggregate(const float* __restrict__ hs, const int* __restrict__ row_start,
                            const int* __restrict__ csr_src, float* __restrict__ agg, int N) {
  int w = (blockIdx.x * blockDim.x + threadIdx.x) >> 6;
  int j = threadIdx.x & 63;
  if (w >= N) return;
  int e = row_start[w];
  int s1 = row_start[w + 1];
  float acc = hs[w * HID + j];  // self loop; final *dinv[d] applied in k_post
  for (; e + 3 < s1; e += 4) {
    int sa = csr_src[e];
    int sb = csr_src[e + 1];
    int sc = csr_src[e + 2];
    int sd = csr_src[e + 3];
    float va = hs[sa * HID + j];
    float vb = hs[sb * HID + j];
    float vc = hs[sc * HID + j];
    float vd = hs[sd * HID + j];
    acc += va; acc += vb; acc += vc; acc += vd;
  }
  for (; e < s1; ++e) acc += hs[csr_src[e] * HID + j];
  agg[w * HID + j] = acc;
}

// v = relu(agg*dinv + b); LN(v)*g+be; out = relu(v @ L + lb)
template<int DOUT>
__global__ void k_post(const float* __restrict__ agg, const float* __restrict__ dinv,
                       const float* __restrict__ b, const float* __restrict__ g,
                       const float* __restrict__ be, const float* __restrict__ L,
                       const float* __restrict__ lb, float* __restrict__ xout, int N) {
  __shared__ float Ll[HID * DOUT];
  __shared__ float lbl[DOUT];
  __shared__ float bl[HID], gl[HID], bel[HID];
  __shared__ float vall[4 * HID];
  int t = threadIdx.x;
  for (int i = t; i < HID * DOUT; i += 256) Ll[i] = L[i];
  if (t < HID) { bl[t] = b[t]; gl[t] = g[t]; bel[t] = be[t]; }
  if (t < DOUT) lbl[t] = lb[t];
  __syncthreads();
  int w = t >> 6, j = t & 63;
  int row = blockIdx.x * 4 + w;
  if (row >= N) return;
  float v = agg[row * HID + j] * dinv[row] + bl[j];
  v = fmaxf(v, 0.f);
  float s = v;
  #pragma unroll
  for (int m = 1; m < 64; m <<= 1) s += __shfl_xor(s, m);
  float mu = s * (1.f / 64.f);
  float d = v - mu;
  float q = d * d;
  #pragma unroll
  for (int m = 1; m < 64; m <<= 1) q += __shfl_xor(q, m);
  float inv = rsqrtf(q * (1.f / 64.f) + 1e-5f);
  float nv = d * inv * gl[j] + bel[j];
  vall[w * 64 + j] = nv;  // wave-local segment: same-wave RAW
  if (j < DOUT) {
    float o = lbl[j];
    #pragma unroll
    for (int k = 0; k < HID; ++k) o += vall[w * 64 + k] * Ll[k * DOUT + j];
    o = fmaxf(o, 0.f);
    xout[row * DOUT + j] = o;
  }
}

__global__ void k_colmax(const float* __restrict__ x, int N, int D, float* __restrict__ out) {
  int j = threadIdx.x;
  if (j >= D) return;
  float m = 0.f;
  for (int r = blockIdx.x; r < N; r += gridDim.x) m = fmaxf(m, x[r * D + j]);
  atomicMax((int*)&out[j], __float_as_int(m));
}

extern "C" void kernel_launch(void* const* d_in, const int* in_sizes, int n_in,
                              void* d_out, int out_size, void* d_ws, size_t ws_size,
                              hipStream_t stream) {
  const float* x = (const float*)d_in[0];
  const int* ei = (const int*)d_in[1];
  int N = in_sizes[0] / 6;
  int E = in_sizes[1] / 2;
  const int* src = ei;
  const int* dst = ei + E;

  const float *W[3], *b[3], *g[3], *be[3], *L[3], *lb[3];
  for (int l = 0; l < 3; ++l) {
    W[l]  = (const float*)d_in[2 + 6 * l + 0];
    b[l]  = (const float*)d_in[2 + 6 * l + 1];
    g[l]  = (const float*)d_in[2 + 6 * l + 2];
    be[l] = (const float*)d_in[2 + 6 * l + 3];
    L[l]  = (const float*)d_in[2 + 6 * l + 4];
    lb[l] = (const float*)d_in[2 + 6 * l + 5];
  }

  char* p = (char*)d_ws;
  auto alloc = [&](size_t bytes) {
    char* r = p;
    p += (bytes + 255) & ~size_t(255);
    return r;
  };
  int* cnt       = (int*)alloc(sizeof(int) * N);
  int* row_start = (int*)alloc(sizeof(int) * (size_t)(N + 1));
  int* cursor    = (int*)alloc(sizeof(int) * N);
  int* csr_src   = (int*)alloc(sizeof(int) * E);
  float* dinv    = (float*)alloc(sizeof(float) * N);
  int* blocksum  = (int*)alloc(sizeof(int) * SCAN_B);
  int* bucket_cur= (int*)alloc(sizeof(int) * NBMAX);
  float* bufA    = (float*)alloc(sizeof(float) * (size_t)N * HID);
  float* bufB    = (float*)alloc(sizeof(float) * (size_t)N * HID);
  float* out1    = (float*)alloc(sizeof(float) * (size_t)N * 12);
  float* out2    = (float*)alloc(sizeof(float) * (size_t)N * 24);
  float* out3    = bufA;                 // layer-3 k_post doesn't read bufA
  uint2* part    = (uint2*)bufA;         // setup-phase only; bufA first written after fill

  float* dout = (float*)d_out;

  const int tpb = 256;
  int nb = (N + SCAN_B - 1) / SCAN_B;
  int nbk = (N + (1 << BSHIFT) - 1) >> BSHIFT;  // buckets actually used
  k_init<<<(N + tpb - 1) / tpb, tpb, 0, stream>>>(cnt, N, dout, out_size);
  k_count<<<(E + tpb - 1) / tpb, tpb, 0, stream>>>(dst, E, cnt);
  k_scan1<<<nb, SCAN_B, 0, stream>>>(cnt, N, row_start, blocksum);
  k_scan2<<<1, SCAN_B, 0, stream>>>(blocksum, nb);
  k_scan3<<<(N + tpb - 1) / tpb, tpb, 0, stream>>>(cnt, blocksum, N, E, row_start, cursor, dinv, bucket_cur);
  k_part<<<(E + EPB - 1) / EPB, 256, 0, stream>>>(src, dst, E, bucket_cur, part);
  k_fill2<<<nbk * SPLIT, 256, 0, stream>>>(part, row_start, N, cursor, csr_src);

  int rb = (N + 3) / 4;  // 4 rows (waves) per 256-thread block

  // layer 1: x[N,6] -> out1[N,12]
  k_mm_in<6><<<rb, 256, 0, stream>>>(x, W[0], dinv, bufA, N);
  k_aggregate<<<rb, 256, 0, stream>>>(bufA, row_start, csr_src, bufB, N);
  k_post<12><<<rb, 256, 0, stream>>>(bufB, dinv, b[0], g[0], be[0], L[0], lb[0], out1, N);

  // layer 2: out1[N,12] -> out2[N,24]
  k_mm_in<12><<<rb, 256, 0, stream>>>(out1, W[1], dinv, bufA, N);
  k_aggregate<<<rb, 256, 0, stream>>>(bufA, row_start, csr_src, bufB, N);
  k_post<24><<<rb, 256, 0, stream>>>(bufB, dinv, b[1], g[1], be[1], L[1], lb[1], out2, N);

  // layer 3: out2[N,24] -> out3[N,48]
  k_mm_in<24><<<rb, 256, 0, stream>>>(out2, W[2], dinv, bufA, N);
  k_aggregate<<<rb, 256, 0, stream>>>(bufA, row_start, csr_src, bufB, N);
  k_post<48><<<rb, 256, 0, stream>>>(bufB, dinv, b[2], g[2], be[2], L[2], lb[2], out3, N);

  k_colmax<<<1024, 64, 0, stream>>>(out3, N, 48, dout);
}

// Round 4
// 613.725 us; speedup vs baseline: 1.8607x; 1.2159x over previous
//
#include <hip/hip_runtime.h>

constexpr int HID = 64;
constexpr int SCAN_B = 1024;   // elements per scan1 block
constexpr int BSHIFT = 9;      // bucket = dst >> 9  (512 nodes per bucket)
constexpr int NBMAX = 256;     // max buckets (N=100k -> 196)
constexpr int EPB = 4096;      // edges per k_part block
constexpr int SPLIT = 4;

__global__ void k_init(int* __restrict__ cnt, int n, float* __restrict__ out, int d) {
  int i = blockIdx.x * blockDim.x + threadIdx.x;
  if (i < n) cnt[i] = 0;
  if (i < d) out[i] = 0.f;
}

__global__ void k_count(const int* __restrict__ dst, int E, int* __restrict__ cnt) {
  int e = blockIdx.x * blockDim.x + threadIdx.x;
  if (e < E) atomicAdd(&cnt[dst[e]], 1);
}

__global__ __launch_bounds__(1024)
void k_scan1(const int* __restrict__ cnt, int N,
             int* __restrict__ row_start, int* __restrict__ blocksum) {
  __shared__ int sm[SCAN_B];
  int t = threadIdx.x;
  int i = blockIdx.x * SCAN_B + t;
  int v = (i < N) ? cnt[i] : 0;
  sm[t] = v;
  __syncthreads();
  for (int off = 1; off < SCAN_B; off <<= 1) {
    int u = (t >= off) ? sm[t - off] : 0;
    __syncthreads();
    sm[t] += u;
    __syncthreads();
  }
  if (i < N) row_start[i] = sm[t] - v;
  if (t == SCAN_B - 1) blocksum[blockIdx.x] = sm[t];
}

__global__ __launch_bounds__(1024)
void k_scan2(int* __restrict__ blocksum, int nb) {
  __shared__ int sm[SCAN_B];
  int t = threadIdx.x;
  int v = (t < nb) ? blocksum[t] : 0;
  sm[t] = v;
  __syncthreads();
  for (int off = 1; off < SCAN_B; off <<= 1) {
    int u = (t >= off) ? sm[t - off] : 0;
    __syncthreads();
    sm[t] += u;
    __syncthreads();
  }
  if (t < nb) blocksum[t] = sm[t] - v;
}

__global__ void k_scan3(const int* __restrict__ cnt, const int* __restrict__ blocksum,
                        int N, int E, int* __restrict__ row_start,
                        int* __restrict__ cursor, float* __restrict__ dinv,
                        int* __restrict__ bucket_cur) {
  int i = blockIdx.x * blockDim.x + threadIdx.x;
  if (i >= N) return;
  int rs = row_start[i] + blocksum[i / SCAN_B];
  row_start[i] = rs;
  cursor[i] = rs;
  dinv[i] = rsqrtf((float)(cnt[i] + 1));
  if ((i & ((1 << BSHIFT) - 1)) == 0) bucket_cur[i >> BSHIFT] = rs;
  if (i == 0) row_start[N] = E;
}

__global__ __launch_bounds__(256)
void k_part(const int* __restrict__ src, const int* __restrict__ dst, int E,
            int* __restrict__ bucket_cur, uint2* __restrict__ part) {
  __shared__ int lcnt[NBMAX];
  __shared__ int lcur[NBMAX];
  int t = threadIdx.x;
  int base = blockIdx.x * EPB;
  for (int i = t; i < NBMAX; i += 256) lcnt[i] = 0;
  __syncthreads();
  #pragma unroll
  for (int i = 0; i < EPB / 256; ++i) {
    int e = base + i * 256 + t;
    if (e < E) atomicAdd(&lcnt[dst[e] >> BSHIFT], 1);
  }
  __syncthreads();
  for (int i = t; i < NBMAX; i += 256)
    lcur[i] = lcnt[i] ? atomicAdd(&bucket_cur[i], lcnt[i]) : 0;
  __syncthreads();
  #pragma unroll
  for (int i = 0; i < EPB / 256; ++i) {
    int e = base + i * 256 + t;
    if (e < E) {
      int s = src[e], d = dst[e];
      int pos = atomicAdd(&lcur[d >> BSHIFT], 1);
      part[pos] = make_uint2((unsigned)s, (unsigned)d);
    }
  }
}

__global__ __launch_bounds__(256)
void k_fill2(const uint2* __restrict__ part, const int* __restrict__ row_start,
             int N, int* __restrict__ cursor, int* __restrict__ csr_src) {
  int b = blockIdx.x / SPLIT;
  int s = blockIdx.x % SPLIT;
  int lo_node = b << BSHIFT;
  int hi_node = min(lo_node + (1 << BSHIFT), N);
  if (lo_node >= N) return;
  int lo = row_start[lo_node];
  int hi = row_start[hi_node];
  int len = hi - lo;
  int chunk = (len + SPLIT - 1) / SPLIT;
  int clo = lo + s * chunk;
  int chi = min(clo + chunk, hi);
  for (int e = clo + threadIdx.x; e < chi; e += 256) {
    uint2 u = part[e];
    int pos = atomicAdd(&cursor[u.y], 1);
    csr_src[pos] = (int)u.x;
  }
}

// Precompute gL[k][j] = g[k]*L[k][j] and cj[j] = lb[j] + sum_k be[k]*L[k][j], all 3 layers.
__global__ void k_prep(const float* __restrict__ g1, const float* __restrict__ be1,
                       const float* __restrict__ L1, const float* __restrict__ lb1,
                       const float* __restrict__ g2, const float* __restrict__ be2,
                       const float* __restrict__ L2, const float* __restrict__ lb2,
                       const float* __restrict__ g3, const float* __restrict__ be3,
                       const float* __restrict__ L3, const float* __restrict__ lb3,
                       float* __restrict__ gL1, float* __restrict__ cj1,
                       float* __restrict__ gL2, float* __restrict__ cj2,
                       float* __restrict__ gL3, float* __restrict__ cj3) {
  int t = blockIdx.x * blockDim.x + threadIdx.x;
  if (t < 768) gL1[t] = g1[t / 12] * L1[t];
  else if (t < 768 + 1536) { int i = t - 768;  gL2[i] = g2[i / 24] * L2[i]; }
  else if (t < 2304 + 3072) { int i = t - 2304; gL3[i] = g3[i / 48] * L3[i]; }
  else if (t < 5376 + 84) {
    int i = t - 5376;
    if (i < 12) {
      float s = lb1[i];
      for (int k = 0; k < HID; ++k) s += be1[k] * L1[k * 12 + i];
      cj1[i] = s;
    } else if (i < 36) {
      int j = i - 12;
      float s = lb2[j];
      for (int k = 0; k < HID; ++k) s += be2[k] * L2[k * 24 + j];
      cj2[j] = s;
    } else {
      int j = i - 36;
      float s = lb3[j];
      for (int k = 0; k < HID; ++k) s += be3[k] * L3[k * 48 + j];
      cj3[j] = s;
    }
  }
}

// lane=row input GEMM: hs[row][j] = (x[row] @ W)[j] * dinv[row]. W reads are
// wave-uniform compile-time offsets -> s_load; inner loop pure full-lane v_fma.
template<int DIN>
__global__ __launch_bounds__(64)
void k_mm2(const float* __restrict__ xin, const float* __restrict__ W,
           const float* __restrict__ dinv, float* __restrict__ hs, int N) {
  int row = blockIdx.x * 64 + threadIdx.x;
  bool act = row < N;
  int r = act ? row : (N - 1);
  float v[DIN];
  if constexpr (DIN % 4 == 0) {
    const float4* xp = (const float4*)(xin + (size_t)r * DIN);
    #pragma unroll
    for (int c = 0; c < DIN / 4; ++c) {
      float4 t4 = xp[c];
      v[4 * c + 0] = t4.x; v[4 * c + 1] = t4.y; v[4 * c + 2] = t4.z; v[4 * c + 3] = t4.w;
    }
  } else {
    const float2* xp = (const float2*)(xin + (size_t)r * DIN);
    #pragma unroll
    for (int c = 0; c < DIN / 2; ++c) {
      float2 t2 = xp[c];
      v[2 * c + 0] = t2.x; v[2 * c + 1] = t2.y;
    }
  }
  float acc[HID];
  #pragma unroll
  for (int j = 0; j < HID; ++j) acc[j] = 0.f;
  #pragma unroll
  for (int k = 0; k < DIN; ++k) {
    float a = v[k];
    #pragma unroll
    for (int j = 0; j < HID; ++j) acc[j] = fmaf(a, W[k * HID + j], acc[j]);
  }
  if (act) {
    float di = dinv[row];
    float4* op = (float4*)(hs + (size_t)row * HID);
    #pragma unroll
    for (int c = 0; c < HID / 4; ++c)
      op[c] = make_float4(acc[4 * c] * di, acc[4 * c + 1] * di,
                          acc[4 * c + 2] * di, acc[4 * c + 3] * di);
  }
}

// agg[d, j] = hs[d, j] + sum_{s in in(d)} hs[s, j]   (one wave per node, lane = feature)
__global__ void k_aggregate(const float* __restrict__ hs, const int* __restrict__ row_start,
                            const int* __restrict__ csr_src, float* __restrict__ agg, int N) {
  int w = (blockIdx.x * blockDim.x + threadIdx.x) >> 6;
  int j = threadIdx.x & 63;
  if (w >= N) return;
  int e = row_start[w];
  int s1 = row_start[w + 1];
  float acc = hs[w * HID + j];  // self loop; final *dinv[d] applied in k_post2
  for (; e + 3 < s1; e += 4) {
    int sa = csr_src[e];
    int sb = csr_src[e + 1];
    int sc = csr_src[e + 2];
    int sd = csr_src[e + 3];
    float va = hs[sa * HID + j];
    float vb = hs[sb * HID + j];
    float vc = hs[sc * HID + j];
    float vd = hs[sd * HID + j];
    acc += va; acc += vb; acc += vc; acc += vd;
  }
  for (; e < s1; ++e) acc += hs[csr_src[e] * HID + j];
  agg[w * HID + j] = acc;
}

// lane=row fused epilogue: v = relu(agg*dinv + b); LN stats in-register;
// out = relu(inv*(d @ gL) + cj). gL/cj/b are uniform s_loads; inner = pure v_fma.
template<int DOUT>
__global__ __launch_bounds__(64)
void k_post2(const float* __restrict__ agg, const float* __restrict__ dinv,
             const float* __restrict__ b, const float* __restrict__ gL,
             const float* __restrict__ cj, float* __restrict__ xout, int N) {
  int row = blockIdx.x * 64 + threadIdx.x;
  bool act = row < N;
  int r = act ? row : (N - 1);
  float v[HID];
  const float4* ap = (const float4*)(agg + (size_t)r * HID);
  #pragma unroll
  for (int c = 0; c < HID / 4; ++c) {
    float4 t4 = ap[c];
    v[4 * c + 0] = t4.x; v[4 * c + 1] = t4.y; v[4 * c + 2] = t4.z; v[4 * c + 3] = t4.w;
  }
  float di = dinv[r];
  float s0 = 0.f, s1 = 0.f, s2 = 0.f, s3 = 0.f;
  #pragma unroll
  for (int k = 0; k < HID; k += 4) {
    v[k]     = fmaxf(fmaf(v[k],     di, b[k]),     0.f); s0 += v[k];
    v[k + 1] = fmaxf(fmaf(v[k + 1], di, b[k + 1]), 0.f); s1 += v[k + 1];
    v[k + 2] = fmaxf(fmaf(v[k + 2], di, b[k + 2]), 0.f); s2 += v[k + 2];
    v[k + 3] = fmaxf(fmaf(v[k + 3], di, b[k + 3]), 0.f); s3 += v[k + 3];
  }
  float mu = ((s0 + s1) + (s2 + s3)) * (1.f / 64.f);
  float q0 = 0.f, q1 = 0.f, q2 = 0.f, q3 = 0.f;
  #pragma unroll
  for (int k = 0; k < HID; k += 4) {
    float d0 = v[k] - mu, d1 = v[k + 1] - mu, d2 = v[k + 2] - mu, d3 = v[k + 3] - mu;
    v[k] = d0; v[k + 1] = d1; v[k + 2] = d2; v[k + 3] = d3;
    q0 = fmaf(d0, d0, q0); q1 = fmaf(d1, d1, q1);
    q2 = fmaf(d2, d2, q2); q3 = fmaf(d3, d3, q3);
  }
  float inv = rsqrtf(((q0 + q1) + (q2 + q3)) * (1.f / 64.f) + 1e-5f);
  float acc[DOUT];
  #pragma unroll
  for (int j = 0; j < DOUT; ++j) acc[j] = 0.f;
  #pragma unroll
  for (int k = 0; k < HID; ++k) {
    float d = v[k];
    #pragma unroll
    for (int j = 0; j < DOUT; ++j) acc[j] = fmaf(d, gL[k * DOUT + j], acc[j]);
  }
  if (act) {
    float4* op = (float4*)(xout + (size_t)row * DOUT);
    #pragma unroll
    for (int c = 0; c < DOUT / 4; ++c) {
      float o0 = fmaxf(fmaf(inv, acc[4 * c + 0], cj[4 * c + 0]), 0.f);
      float o1 = fmaxf(fmaf(inv, acc[4 * c + 1], cj[4 * c + 1]), 0.f);
      float o2 = fmaxf(fmaf(inv, acc[4 * c + 2], cj[4 * c + 2]), 0.f);
      float o3 = fmaxf(fmaf(inv, acc[4 * c + 3], cj[4 * c + 3]), 0.f);
      op[c] = make_float4(o0, o1, o2, o3);
    }
  }
}

__global__ void k_colmax(const float* __restrict__ x, int N, int D, float* __restrict__ out) {
  int j = threadIdx.x;
  if (j >= D) return;
  float m = 0.f;
  for (int r = blockIdx.x; r < N; r += gridDim.x) m = fmaxf(m, x[r * D + j]);
  atomicMax((int*)&out[j], __float_as_int(m));
}

extern "C" void kernel_launch(void* const* d_in, const int* in_sizes, int n_in,
                              void* d_out, int out_size, void* d_ws, size_t ws_size,
                              hipStream_t stream) {
  const float* x = (const float*)d_in[0];
  const int* ei = (const int*)d_in[1];
  int N = in_sizes[0] / 6;
  int E = in_sizes[1] / 2;
  const int* src = ei;
  const int* dst = ei + E;

  const float *W[3], *b[3], *g[3], *be[3], *L[3], *lb[3];
  for (int l = 0; l < 3; ++l) {
    W[l]  = (const float*)d_in[2 + 6 * l + 0];
    b[l]  = (const float*)d_in[2 + 6 * l + 1];
    g[l]  = (const float*)d_in[2 + 6 * l + 2];
    be[l] = (const float*)d_in[2 + 6 * l + 3];
    L[l]  = (const float*)d_in[2 + 6 * l + 4];
    lb[l] = (const float*)d_in[2 + 6 * l + 5];
  }

  char* p = (char*)d_ws;
  auto alloc = [&](size_t bytes) {
    char* r = p;
    p += (bytes + 255) & ~size_t(255);
    return r;
  };
  int* cnt       = (int*)alloc(sizeof(int) * N);
  int* row_start = (int*)alloc(sizeof(int) * (size_t)(N + 1));
  int* cursor    = (int*)alloc(sizeof(int) * N);
  int* csr_src   = (int*)alloc(sizeof(int) * E);
  float* dinv    = (float*)alloc(sizeof(float) * N);
  int* blocksum  = (int*)alloc(sizeof(int) * SCAN_B);
  int* bucket_cur= (int*)alloc(sizeof(int) * NBMAX);
  float* gL1     = (float*)alloc(sizeof(float) * 64 * 12);
  float* cj1     = (float*)alloc(sizeof(float) * 12);
  float* gL2     = (float*)alloc(sizeof(float) * 64 * 24);
  float* cj2     = (float*)alloc(sizeof(float) * 24);
  float* gL3     = (float*)alloc(sizeof(float) * 64 * 48);
  float* cj3     = (float*)alloc(sizeof(float) * 48);
  float* bufA    = (float*)alloc(sizeof(float) * (size_t)N * HID);
  float* bufB    = (float*)alloc(sizeof(float) * (size_t)N * HID);
  float* out1    = (float*)alloc(sizeof(float) * (size_t)N * 12);
  float* out2    = (float*)alloc(sizeof(float) * (size_t)N * 24);
  float* out3    = bufA;                 // layer-3 k_post2 doesn't read bufA
  uint2* part    = (uint2*)bufA;         // setup-phase only

  float* dout = (float*)d_out;

  const int tpb = 256;
  int nb = (N + SCAN_B - 1) / SCAN_B;
  int nbk = (N + (1 << BSHIFT) - 1) >> BSHIFT;
  k_init<<<(N + tpb - 1) / tpb, tpb, 0, stream>>>(cnt, N, dout, out_size);
  k_prep<<<(5460 + tpb - 1) / tpb, tpb, 0, stream>>>(
      g[0], be[0], L[0], lb[0], g[1], be[1], L[1], lb[1], g[2], be[2], L[2], lb[2],
      gL1, cj1, gL2, cj2, gL3, cj3);
  k_count<<<(E + tpb - 1) / tpb, tpb, 0, stream>>>(dst, E, cnt);
  k_scan1<<<nb, SCAN_B, 0, stream>>>(cnt, N, row_start, blocksum);
  k_scan2<<<1, SCAN_B, 0, stream>>>(blocksum, nb);
  k_scan3<<<(N + tpb - 1) / tpb, tpb, 0, stream>>>(cnt, blocksum, N, E, row_start, cursor, dinv, bucket_cur);
  k_part<<<(E + EPB - 1) / EPB, 256, 0, stream>>>(src, dst, E, bucket_cur, part);
  k_fill2<<<nbk * SPLIT, 256, 0, stream>>>(part, row_start, N, cursor, csr_src);

  int rb = (N + 3) / 4;      // k_aggregate: 4 node-waves per 256-thread block
  int rb64 = (N + 63) / 64;  // lane=row kernels: 64 rows per 64-thread block

  // layer 1
  k_mm2<6><<<rb64, 64, 0, stream>>>(x, W[0], dinv, bufA, N);
  k_aggregate<<<rb, 256, 0, stream>>>(bufA, row_start, csr_src, bufB, N);
  k_post2<12><<<rb64, 64, 0, stream>>>(bufB, dinv, b[0], gL1, cj1, out1, N);

  // layer 2
  k_mm2<12><<<rb64, 64, 0, stream>>>(out1, W[1], dinv, bufA, N);
  k_aggregate<<<rb, 256, 0, stream>>>(bufA, row_start, csr_src, bufB, N);
  k_post2<24><<<rb64, 64, 0, stream>>>(bufB, dinv, b[1], gL2, cj2, out2, N);

  // layer 3
  k_mm2<24><<<rb64, 64, 0, stream>>>(out2, W[2], dinv, bufA, N);
  k_aggregate<<<rb, 256, 0, stream>>>(bufA, row_start, csr_src, bufB, N);
  k_post2<48><<<rb64, 64, 0, stream>>>(bufB, dinv, b[2], gL3, cj3, out3, N);

  k_colmax<<<1024, 64, 0, stream>>>(out3, N, 48, dout);
}

// Round 5
// 540.939 us; speedup vs baseline: 2.1110x; 1.1346x over previous
//
#include <hip/hip_runtime.h>

constexpr int HID = 64;
constexpr int SCAN_B = 1024;   // elements per scan1 block
constexpr int BSHIFT = 9;      // bucket = dst >> 9  (512 nodes per bucket)
constexpr int NBMAX = 256;     // max buckets (N=100k -> 196)
constexpr int EPB = 4096;      // edges per k_part block
constexpr int SPLIT = 4;

__global__ void k_init(int* __restrict__ cnt, int n, float* __restrict__ out, int d) {
  int i = blockIdx.x * blockDim.x + threadIdx.x;
  if (i < n) cnt[i] = 0;
  if (i < d) out[i] = 0.f;
}

__global__ void k_count(const int* __restrict__ dst, int E, int* __restrict__ cnt) {
  int e = blockIdx.x * blockDim.x + threadIdx.x;
  if (e < E) atomicAdd(&cnt[dst[e]], 1);
}

__global__ __launch_bounds__(1024)
void k_scan1(const int* __restrict__ cnt, int N,
             int* __restrict__ row_start, int* __restrict__ blocksum) {
  __shared__ int sm[SCAN_B];
  int t = threadIdx.x;
  int i = blockIdx.x * SCAN_B + t;
  int v = (i < N) ? cnt[i] : 0;
  sm[t] = v;
  __syncthreads();
  for (int off = 1; off < SCAN_B; off <<= 1) {
    int u = (t >= off) ? sm[t - off] : 0;
    __syncthreads();
    sm[t] += u;
    __syncthreads();
  }
  if (i < N) row_start[i] = sm[t] - v;
  if (t == SCAN_B - 1) blocksum[blockIdx.x] = sm[t];
}

__global__ __launch_bounds__(1024)
void k_scan2(int* __restrict__ blocksum, int nb) {
  __shared__ int sm[SCAN_B];
  int t = threadIdx.x;
  int v = (t < nb) ? blocksum[t] : 0;
  sm[t] = v;
  __syncthreads();
  for (int off = 1; off < SCAN_B; off <<= 1) {
    int u = (t >= off) ? sm[t - off] : 0;
    __syncthreads();
    sm[t] += u;
    __syncthreads();
  }
  if (t < nb) blocksum[t] = sm[t] - v;
}

// Stage 3: finalize row_start/cursor/dinv/bucket_cur AND emit y1 = x*dinv padded [N][8].
__global__ void k_scan3(const int* __restrict__ cnt, const int* __restrict__ blocksum,
                        const float* __restrict__ x, int N, int E,
                        int* __restrict__ row_start, int* __restrict__ cursor,
                        float* __restrict__ dinv, int* __restrict__ bucket_cur,
                        float* __restrict__ y1) {
  int i = blockIdx.x * blockDim.x + threadIdx.x;
  if (i >= N) return;
  int rs = row_start[i] + blocksum[i / SCAN_B];
  row_start[i] = rs;
  cursor[i] = rs;
  float di = rsqrtf((float)(cnt[i] + 1));
  dinv[i] = di;
  const float* xr = x + (size_t)i * 6;
  float4* yp = (float4*)(y1 + (size_t)i * 8);
  yp[0] = make_float4(xr[0] * di, xr[1] * di, xr[2] * di, xr[3] * di);
  yp[1] = make_float4(xr[4] * di, xr[5] * di, 0.f, 0.f);
  if ((i & ((1 << BSHIFT) - 1)) == 0) bucket_cur[i >> BSHIFT] = rs;
  if (i == 0) row_start[N] = E;
}

__global__ __launch_bounds__(256)
void k_part(const int* __restrict__ src, const int* __restrict__ dst, int E,
            int* __restrict__ bucket_cur, uint2* __restrict__ part) {
  __shared__ int lcnt[NBMAX];
  __shared__ int lcur[NBMAX];
  int t = threadIdx.x;
  int base = blockIdx.x * EPB;
  for (int i = t; i < NBMAX; i += 256) lcnt[i] = 0;
  __syncthreads();
  #pragma unroll
  for (int i = 0; i < EPB / 256; ++i) {
    int e = base + i * 256 + t;
    if (e < E) atomicAdd(&lcnt[dst[e] >> BSHIFT], 1);
  }
  __syncthreads();
  for (int i = t; i < NBMAX; i += 256)
    lcur[i] = lcnt[i] ? atomicAdd(&bucket_cur[i], lcnt[i]) : 0;
  __syncthreads();
  #pragma unroll
  for (int i = 0; i < EPB / 256; ++i) {
    int e = base + i * 256 + t;
    if (e < E) {
      int s = src[e], d = dst[e];
      int pos = atomicAdd(&lcur[d >> BSHIFT], 1);
      part[pos] = make_uint2((unsigned)s, (unsigned)d);
    }
  }
}

__global__ __launch_bounds__(256)
void k_fill2(const uint2* __restrict__ part, const int* __restrict__ row_start,
             int N, int* __restrict__ cursor, int* __restrict__ csr_src) {
  int b = blockIdx.x / SPLIT;
  int s = blockIdx.x % SPLIT;
  int lo_node = b << BSHIFT;
  int hi_node = min(lo_node + (1 << BSHIFT), N);
  if (lo_node >= N) return;
  int lo = row_start[lo_node];
  int hi = row_start[hi_node];
  int len = hi - lo;
  int chunk = (len + SPLIT - 1) / SPLIT;
  int clo = lo + s * chunk;
  int chi = min(clo + chunk, hi);
  for (int e = clo + threadIdx.x; e < chi; e += 256) {
    uint2 u = part[e];
    int pos = atomicAdd(&cursor[u.y], 1);
    csr_src[pos] = (int)u.x;
  }
}

// Precompute gL[k][j] = g[k]*L[k][j] and cj[j] = lb[j] + sum_k be[k]*L[k][j], all 3 layers.
__global__ void k_prep(const float* __restrict__ g1, const float* __restrict__ be1,
                       const float* __restrict__ L1, const float* __restrict__ lb1,
                       const float* __restrict__ g2, const float* __restrict__ be2,
                       const float* __restrict__ L2, const float* __restrict__ lb2,
                       const float* __restrict__ g3, const float* __restrict__ be3,
                       const float* __restrict__ L3, const float* __restrict__ lb3,
                       float* __restrict__ gL1, float* __restrict__ cj1,
                       float* __restrict__ gL2, float* __restrict__ cj2,
                       float* __restrict__ gL3, float* __restrict__ cj3) {
  int t = blockIdx.x * blockDim.x + threadIdx.x;
  if (t < 768) gL1[t] = g1[t / 12] * L1[t];
  else if (t < 768 + 1536) { int i = t - 768;  gL2[i] = g2[i / 24] * L2[i]; }
  else if (t < 2304 + 3072) { int i = t - 2304; gL3[i] = g3[i / 48] * L3[i]; }
  else if (t < 5376 + 84) {
    int i = t - 5376;
    if (i < 12) {
      float s = lb1[i];
      for (int k = 0; k < HID; ++k) s += be1[k] * L1[k * 12 + i];
      cj1[i] = s;
    } else if (i < 36) {
      int j = i - 12;
      float s = lb2[j];
      for (int k = 0; k < HID; ++k) s += be2[k] * L2[k * 24 + j];
      cj2[j] = s;
    } else {
      int j = i - 36;
      float s = lb3[j];
      for (int k = 0; k < HID; ++k) s += be3[k] * L3[k * 48 + j];
      cj3[j] = s;
    }
  }
}

// Gather-aggregate of pre-scaled features y [N][F] (F=8/16/32 padded).
// One wave per node; lane = edge_slot*F + feat; C=64/F edges in flight per step.
template<int F, int LOGF>
__global__ __launch_bounds__(256)
void k_agg(const float* __restrict__ y, const int* __restrict__ row_start,
           const int* __restrict__ csr, float* __restrict__ agg, int N) {
  constexpr int C = 64 / F;
  int wid = (blockIdx.x * blockDim.x + threadIdx.x) >> 6;
  if (wid >= N) return;
  int lane = threadIdx.x & 63;
  int es = lane >> LOGF;
  int f = lane & (F - 1);
  int e0 = row_start[wid], e1 = row_start[wid + 1];
  float acc = 0.f;
  for (int e = e0 + es; e < e1; e += C) {
    int s = csr[e];
    acc += y[(size_t)s * F + f];
  }
  #pragma unroll
  for (int m = F; m < 64; m <<= 1) acc += __shfl_xor(acc, m);
  if (lane < F) {
    acc += y[(size_t)wid * F + f];  // self loop (y already *dinv[self])
    agg[(size_t)wid * F + f] = acc;
  }
}

// Fused per-row epilogue: h = relu(dinv*(agg@W) + b); LN in-register;
// out = relu(inv*(d@gL) + cj); optionally pre-scale by dinv for next gather.
template<int DIN, int DOUT, int FIN, int FOUT, bool SCALE>
__global__ __launch_bounds__(64)
void k_fpost(const float* __restrict__ agg, const float* __restrict__ dinv,
             const float* __restrict__ W, const float* __restrict__ bb,
             const float* __restrict__ gL, const float* __restrict__ cj,
             float* __restrict__ yout, int N) {
  int row = blockIdx.x * 64 + threadIdx.x;
  bool act = row < N;
  int r = act ? row : N - 1;
  float a[FIN];
  const float4* ap = (const float4*)(agg + (size_t)r * FIN);
  #pragma unroll
  for (int c = 0; c < FIN / 4; ++c) {
    float4 t4 = ap[c];
    a[4 * c + 0] = t4.x; a[4 * c + 1] = t4.y; a[4 * c + 2] = t4.z; a[4 * c + 3] = t4.w;
  }
  float di = dinv[r];
  float h[HID];
  #pragma unroll
  for (int j = 0; j < HID; ++j) h[j] = 0.f;
  #pragma unroll
  for (int k = 0; k < DIN; ++k) {
    float v = a[k];
    #pragma unroll
    for (int j = 0; j < HID; ++j) h[j] = fmaf(v, W[k * HID + j], h[j]);
  }
  float s0 = 0.f, s1 = 0.f, s2 = 0.f, s3 = 0.f;
  #pragma unroll
  for (int k = 0; k < HID; k += 4) {
    h[k]     = fmaxf(fmaf(h[k],     di, bb[k]),     0.f); s0 += h[k];
    h[k + 1] = fmaxf(fmaf(h[k + 1], di, bb[k + 1]), 0.f); s1 += h[k + 1];
    h[k + 2] = fmaxf(fmaf(h[k + 2], di, bb[k + 2]), 0.f); s2 += h[k + 2];
    h[k + 3] = fmaxf(fmaf(h[k + 3], di, bb[k + 3]), 0.f); s3 += h[k + 3];
  }
  float mu = ((s0 + s1) + (s2 + s3)) * (1.f / 64.f);
  float q0 = 0.f, q1 = 0.f, q2 = 0.f, q3 = 0.f;
  #pragma unroll
  for (int k = 0; k < HID; k += 4) {
    float d0 = h[k] - mu, d1 = h[k + 1] - mu, d2 = h[k + 2] - mu, d3 = h[k + 3] - mu;
    h[k] = d0; h[k + 1] = d1; h[k + 2] = d2; h[k + 3] = d3;
    q0 = fmaf(d0, d0, q0); q1 = fmaf(d1, d1, q1);
    q2 = fmaf(d2, d2, q2); q3 = fmaf(d3, d3, q3);
  }
  float inv = rsqrtf(((q0 + q1) + (q2 + q3)) * (1.f / 64.f) + 1e-5f);
  float acc[DOUT];
  #pragma unroll
  for (int j = 0; j < DOUT; ++j) acc[j] = 0.f;
  #pragma unroll
  for (int k = 0; k < HID; ++k) {
    float d = h[k];
    #pragma unroll
    for (int j = 0; j < DOUT; ++j) acc[j] = fmaf(d, gL[k * DOUT + j], acc[j]);
  }
  if (act) {
    float4* op = (float4*)(yout + (size_t)row * FOUT);
    #pragma unroll
    for (int c = 0; c < FOUT / 4; ++c) {
      float o[4];
      #pragma unroll
      for (int u = 0; u < 4; ++u) {
        int j = 4 * c + u;
        float t = 0.f;
        if (j < DOUT) {
          t = fmaxf(fmaf(inv, acc[j], cj[j]), 0.f);
          if (SCALE) t *= di;
        }
        o[u] = t;
      }
      op[c] = make_float4(o[0], o[1], o[2], o[3]);
    }
  }
}

__global__ void k_colmax(const float* __restrict__ x, int N, int D, float* __restrict__ out) {
  int j = threadIdx.x;
  if (j >= D) return;
  float m = 0.f;
  for (int r = blockIdx.x; r < N; r += gridDim.x) m = fmaxf(m, x[r * D + j]);
  atomicMax((int*)&out[j], __float_as_int(m));
}

extern "C" void kernel_launch(void* const* d_in, const int* in_sizes, int n_in,
                              void* d_out, int out_size, void* d_ws, size_t ws_size,
                              hipStream_t stream) {
  const float* x = (const float*)d_in[0];
  const int* ei = (const int*)d_in[1];
  int N = in_sizes[0] / 6;
  int E = in_sizes[1] / 2;
  const int* src = ei;
  const int* dst = ei + E;

  const float *W[3], *b[3], *g[3], *be[3], *L[3], *lb[3];
  for (int l = 0; l < 3; ++l) {
    W[l]  = (const float*)d_in[2 + 6 * l + 0];
    b[l]  = (const float*)d_in[2 + 6 * l + 1];
    g[l]  = (const float*)d_in[2 + 6 * l + 2];
    be[l] = (const float*)d_in[2 + 6 * l + 3];
    L[l]  = (const float*)d_in[2 + 6 * l + 4];
    lb[l] = (const float*)d_in[2 + 6 * l + 5];
  }

  char* p = (char*)d_ws;
  auto alloc = [&](size_t bytes) {
    char* r = p;
    p += (bytes + 255) & ~size_t(255);
    return r;
  };
  int* cnt       = (int*)alloc(sizeof(int) * N);
  int* row_start = (int*)alloc(sizeof(int) * (size_t)(N + 1));
  int* cursor    = (int*)alloc(sizeof(int) * N);
  int* csr_src   = (int*)alloc(sizeof(int) * E);
  float* dinv    = (float*)alloc(sizeof(float) * N);
  int* blocksum  = (int*)alloc(sizeof(int) * SCAN_B);
  int* bucket_cur= (int*)alloc(sizeof(int) * NBMAX);
  float* gL1     = (float*)alloc(sizeof(float) * 64 * 12);
  float* cj1     = (float*)alloc(sizeof(float) * 12);
  float* gL2     = (float*)alloc(sizeof(float) * 64 * 24);
  float* cj2     = (float*)alloc(sizeof(float) * 24);
  float* gL3     = (float*)alloc(sizeof(float) * 64 * 48);
  float* cj3     = (float*)alloc(sizeof(float) * 48);
  float* y1      = (float*)alloc(sizeof(float) * (size_t)N * 8);
  float* y2      = (float*)alloc(sizeof(float) * (size_t)N * 16);
  size_t y3_bytes = sizeof(float) * (size_t)N * 32;
  size_t part_bytes = sizeof(uint2) * (size_t)E;
  float* y3      = (float*)alloc(y3_bytes > part_bytes ? y3_bytes : part_bytes);
  float* aggb    = (float*)alloc(sizeof(float) * (size_t)N * 32);
  float* out3    = (float*)alloc(sizeof(float) * (size_t)N * 48);
  uint2* part    = (uint2*)y3;  // setup-phase only; y3 first written by layer-2 fpost

  float* dout = (float*)d_out;

  const int tpb = 256;
  int nb = (N + SCAN_B - 1) / SCAN_B;
  int nbk = (N + (1 << BSHIFT) - 1) >> BSHIFT;
  k_init<<<(N + tpb - 1) / tpb, tpb, 0, stream>>>(cnt, N, dout, out_size);
  k_prep<<<(5460 + tpb - 1) / tpb, tpb, 0, stream>>>(
      g[0], be[0], L[0], lb[0], g[1], be[1], L[1], lb[1], g[2], be[2], L[2], lb[2],
      gL1, cj1, gL2, cj2, gL3, cj3);
  k_count<<<(E + tpb - 1) / tpb, tpb, 0, stream>>>(dst, E, cnt);
  k_scan1<<<nb, SCAN_B, 0, stream>>>(cnt, N, row_start, blocksum);
  k_scan2<<<1, SCAN_B, 0, stream>>>(blocksum, nb);
  k_scan3<<<(N + tpb - 1) / tpb, tpb, 0, stream>>>(cnt, blocksum, x, N, E,
                                                   row_start, cursor, dinv, bucket_cur, y1);
  k_part<<<(E + EPB - 1) / EPB, 256, 0, stream>>>(src, dst, E, bucket_cur, part);
  k_fill2<<<nbk * SPLIT, 256, 0, stream>>>(part, row_start, N, cursor, csr_src);

  int rb = (N + 3) / 4;      // k_agg: 4 node-waves per 256-thread block
  int rb64 = (N + 63) / 64;  // k_fpost: 64 rows per 64-thread block

  // layer 1: y1[N,8] -> agg -> fpost -> y2[N,16] (pre-scaled by dinv)
  k_agg<8, 3><<<rb, 256, 0, stream>>>(y1, row_start, csr_src, aggb, N);
  k_fpost<6, 12, 8, 16, true><<<rb64, 64, 0, stream>>>(aggb, dinv, W[0], b[0], gL1, cj1, y2, N);

  // layer 2: y2 -> agg -> fpost -> y3[N,32] (pre-scaled)
  k_agg<16, 4><<<rb, 256, 0, stream>>>(y2, row_start, csr_src, aggb, N);
  k_fpost<12, 24, 16, 32, true><<<rb64, 64, 0, stream>>>(aggb, dinv, W[1], b[1], gL2, cj2, y3, N);

  // layer 3: y3 -> agg -> fpost -> out3[N,48] (raw)
  k_agg<32, 5><<<rb, 256, 0, stream>>>(y3, row_start, csr_src, aggb, N);
  k_fpost<24, 48, 32, 48, false><<<rb64, 64, 0, stream>>>(aggb, dinv, W[2], b[2], gL3, cj3, out3, N);

  k_colmax<<<1024, 64, 0, stream>>>(out3, N, 48, dout);
}

// Round 6
// 469.201 us; speedup vs baseline: 2.4338x; 1.1529x over previous
//
#include <hip/hip_runtime.h>

constexpr int HID = 64;
constexpr int SCAN_B = 1024;   // elements per scan1 block
constexpr int BSHIFT = 9;      // bucket = dst >> 9  (512 nodes per bucket)
constexpr int NBMAX = 256;     // max buckets (N=100k -> 196)
constexpr int EPB = 4096;      // edges per k_part block
constexpr int SPLIT = 4;

__global__ void k_init(int* __restrict__ cnt, int n, float* __restrict__ out, int d) {
  int i = blockIdx.x * blockDim.x + threadIdx.x;
  if (i < n) cnt[i] = 0;
  if (i < d) out[i] = 0.f;
}

// 4 edges per thread via int4 (dst is 16B-aligned: base + E*4 bytes, E=1.6M).
__global__ void k_count(const int* __restrict__ dst, int E, int* __restrict__ cnt) {
  int i = blockIdx.x * blockDim.x + threadIdx.x;
  int e = i * 4;
  if (e + 3 < E) {
    int4 d = ((const int4*)dst)[i];
    atomicAdd(&cnt[d.x], 1); atomicAdd(&cnt[d.y], 1);
    atomicAdd(&cnt[d.z], 1); atomicAdd(&cnt[d.w], 1);
  } else {
    for (; e < E; ++e) atomicAdd(&cnt[dst[e]], 1);
  }
}

__global__ __launch_bounds__(1024)
void k_scan1(const int* __restrict__ cnt, int N,
             int* __restrict__ row_start, int* __restrict__ blocksum) {
  __shared__ int sm[SCAN_B];
  int t = threadIdx.x;
  int i = blockIdx.x * SCAN_B + t;
  int v = (i < N) ? cnt[i] : 0;
  sm[t] = v;
  __syncthreads();
  for (int off = 1; off < SCAN_B; off <<= 1) {
    int u = (t >= off) ? sm[t - off] : 0;
    __syncthreads();
    sm[t] += u;
    __syncthreads();
  }
  if (i < N) row_start[i] = sm[t] - v;
  if (t == SCAN_B - 1) blocksum[blockIdx.x] = sm[t];
}

__global__ __launch_bounds__(1024)
void k_scan2(int* __restrict__ blocksum, int nb) {
  __shared__ int sm[SCAN_B];
  int t = threadIdx.x;
  int v = (t < nb) ? blocksum[t] : 0;
  sm[t] = v;
  __syncthreads();
  for (int off = 1; off < SCAN_B; off <<= 1) {
    int u = (t >= off) ? sm[t - off] : 0;
    __syncthreads();
    sm[t] += u;
    __syncthreads();
  }
  if (t < nb) blocksum[t] = sm[t] - v;
}

// Stage 3: finalize row_start/cursor/dinv/bucket_cur AND emit y1 = x*dinv padded [N][8].
__global__ void k_scan3(const int* __restrict__ cnt, const int* __restrict__ blocksum,
                        const float* __restrict__ x, int N, int E,
                        int* __restrict__ row_start, int* __restrict__ cursor,
                        float* __restrict__ dinv, int* __restrict__ bucket_cur,
                        float* __restrict__ y1) {
  int i = blockIdx.x * blockDim.x + threadIdx.x;
  if (i >= N) return;
  int rs = row_start[i] + blocksum[i / SCAN_B];
  row_start[i] = rs;
  cursor[i] = rs;
  float di = rsqrtf((float)(cnt[i] + 1));
  dinv[i] = di;
  const float* xr = x + (size_t)i * 6;
  float4* yp = (float4*)(y1 + (size_t)i * 8);
  yp[0] = make_float4(xr[0] * di, xr[1] * di, xr[2] * di, xr[3] * di);
  yp[1] = make_float4(xr[4] * di, xr[5] * di, 0.f, 0.f);
  if ((i & ((1 << BSHIFT) - 1)) == 0) bucket_cur[i >> BSHIFT] = rs;
  if (i == 0) row_start[N] = E;
}

// Single-pass partition: int4 edge loads cached in registers (16 edges/thread).
__global__ __launch_bounds__(256)
void k_part(const int* __restrict__ src, const int* __restrict__ dst, int E,
            int* __restrict__ bucket_cur, uint2* __restrict__ part) {
  __shared__ int lcnt[NBMAX];
  __shared__ int lcur[NBMAX];
  int t = threadIdx.x;
  int base = blockIdx.x * EPB;
  for (int i = t; i < NBMAX; i += 256) lcnt[i] = 0;
  __syncthreads();
  bool full = (base + EPB) <= E;
  int4 sv[4], dv[4];
  if (full) {
    const int4* src4 = (const int4*)src;
    const int4* dst4 = (const int4*)dst;
    #pragma unroll
    for (int u = 0; u < 4; ++u) {
      int q = (base >> 2) + u * 256 + t;
      sv[u] = src4[q];
      dv[u] = dst4[q];
    }
    #pragma unroll
    for (int u = 0; u < 4; ++u) {
      atomicAdd(&lcnt[dv[u].x >> BSHIFT], 1);
      atomicAdd(&lcnt[dv[u].y >> BSHIFT], 1);
      atomicAdd(&lcnt[dv[u].z >> BSHIFT], 1);
      atomicAdd(&lcnt[dv[u].w >> BSHIFT], 1);
    }
  } else {
    for (int u = 0; u < 16; ++u) {
      int e = base + u * 256 + t;
      if (e < E) atomicAdd(&lcnt[dst[e] >> BSHIFT], 1);
    }
  }
  __syncthreads();
  for (int i = t; i < NBMAX; i += 256)
    lcur[i] = lcnt[i] ? atomicAdd(&bucket_cur[i], lcnt[i]) : 0;
  __syncthreads();
  if (full) {
    #pragma unroll
    for (int u = 0; u < 4; ++u) {
      int pos;
      pos = atomicAdd(&lcur[dv[u].x >> BSHIFT], 1);
      part[pos] = make_uint2((unsigned)sv[u].x, (unsigned)dv[u].x);
      pos = atomicAdd(&lcur[dv[u].y >> BSHIFT], 1);
      part[pos] = make_uint2((unsigned)sv[u].y, (unsigned)dv[u].y);
      pos = atomicAdd(&lcur[dv[u].z >> BSHIFT], 1);
      part[pos] = make_uint2((unsigned)sv[u].z, (unsigned)dv[u].z);
      pos = atomicAdd(&lcur[dv[u].w >> BSHIFT], 1);
      part[pos] = make_uint2((unsigned)sv[u].w, (unsigned)dv[u].w);
    }
  } else {
    for (int u = 0; u < 16; ++u) {
      int e = base + u * 256 + t;
      if (e < E) {
        int s = src[e], d = dst[e];
        int pos = atomicAdd(&lcur[d >> BSHIFT], 1);
        part[pos] = make_uint2((unsigned)s, (unsigned)d);
      }
    }
  }
}

__global__ __launch_bounds__(256)
void k_fill2(const uint2* __restrict__ part, const int* __restrict__ row_start,
             int N, int* __restrict__ cursor, int* __restrict__ csr_src) {
  int b = blockIdx.x / SPLIT;
  int s = blockIdx.x % SPLIT;
  int lo_node = b << BSHIFT;
  int hi_node = min(lo_node + (1 << BSHIFT), N);
  if (lo_node >= N) return;
  int lo = row_start[lo_node];
  int hi = row_start[hi_node];
  int len = hi - lo;
  int chunk = (len + SPLIT - 1) / SPLIT;
  int clo = lo + s * chunk;
  int chi = min(clo + chunk, hi);
  for (int e = clo + threadIdx.x; e < chi; e += 256) {
    uint2 u = part[e];
    int pos = atomicAdd(&cursor[u.y], 1);
    csr_src[pos] = (int)u.x;
  }
}

// Precompute gL[k][j] = g[k]*L[k][j] and cj[j] = lb[j] + sum_k be[k]*L[k][j], all 3 layers.
__global__ void k_prep(const float* __restrict__ g1, const float* __restrict__ be1,
                       const float* __restrict__ L1, const float* __restrict__ lb1,
                       const float* __restrict__ g2, const float* __restrict__ be2,
                       const float* __restrict__ L2, const float* __restrict__ lb2,
                       const float* __restrict__ g3, const float* __restrict__ be3,
                       const float* __restrict__ L3, const float* __restrict__ lb3,
                       float* __restrict__ gL1, float* __restrict__ cj1,
                       float* __restrict__ gL2, float* __restrict__ cj2,
                       float* __restrict__ gL3, float* __restrict__ cj3) {
  int t = blockIdx.x * blockDim.x + threadIdx.x;
  if (t < 768) gL1[t] = g1[t / 12] * L1[t];
  else if (t < 768 + 1536) { int i = t - 768;  gL2[i] = g2[i / 24] * L2[i]; }
  else if (t < 2304 + 3072) { int i = t - 2304; gL3[i] = g3[i / 48] * L3[i]; }
  else if (t < 5376 + 84) {
    int i = t - 5376;
    if (i < 12) {
      float s = lb1[i];
      for (int k = 0; k < HID; ++k) s += be1[k] * L1[k * 12 + i];
      cj1[i] = s;
    } else if (i < 36) {
      int j = i - 12;
      float s = lb2[j];
      for (int k = 0; k < HID; ++k) s += be2[k] * L2[k * 24 + j];
      cj2[j] = s;
    } else {
      int j = i - 36;
      float s = lb3[j];
      for (int k = 0; k < HID; ++k) s += be3[k] * L3[k * 48 + j];
      cj3[j] = s;
    }
  }
}

// Gather-aggregate of pre-scaled features y [N][F] (F=8/16/32 padded).
// One wave per node; lane = edge_slot*F + feat. U*C = 16 edges issued per
// iteration (batched loads, clamped-index + zero-mask predication) so the
// typical (deg~16) row completes in ONE gather round -> latency hidden.
template<int F, int LOGF, int U>
__global__ __launch_bounds__(256)
void k_agg(const float* __restrict__ y, const int* __restrict__ row_start,
           const int* __restrict__ csr, float* __restrict__ agg, int N) {
  constexpr int C = 64 / F;
  int wid = (blockIdx.x * blockDim.x + threadIdx.x) >> 6;
  if (wid >= N) return;
  int lane = threadIdx.x & 63;
  int es = lane >> LOGF;
  int f = lane & (F - 1);
  int e0 = row_start[wid], e1 = row_start[wid + 1];
  float acc = 0.f;
  for (int e = e0 + es; e < e1; e += U * C) {
    float v[U];
    #pragma unroll
    for (int u = 0; u < U; ++u) {
      int ee = e + u * C;
      int ec = min(ee, e1 - 1);
      int s = csr[ec];
      float val = y[(size_t)s * F + f];
      v[u] = (ee < e1) ? val : 0.f;
    }
    #pragma unroll
    for (int u = 0; u < U; ++u) acc += v[u];
  }
  #pragma unroll
  for (int m = F; m < 64; m <<= 1) acc += __shfl_xor(acc, m);
  if (lane < F) {
    acc += y[(size_t)wid * F + f];  // self loop (y already *dinv[self])
    agg[(size_t)wid * F + f] = acc;
  }
}

// Fused per-row epilogue: h = relu(dinv*(agg@W) + b); LN in-register;
// out = relu(inv*(d@gL) + cj); optionally pre-scale by dinv for next gather.
template<int DIN, int DOUT, int FIN, int FOUT, bool SCALE>
__global__ __launch_bounds__(64)
void k_fpost(const float* __restrict__ agg, const float* __restrict__ dinv,
             const float* __restrict__ W, const float* __restrict__ bb,
             const float* __restrict__ gL, const float* __restrict__ cj,
             float* __restrict__ yout, int N) {
  int row = blockIdx.x * 64 + threadIdx.x;
  bool act = row < N;
  int r = act ? row : N - 1;
  float a[FIN];
  const float4* ap = (const float4*)(agg + (size_t)r * FIN);
  #pragma unroll
  for (int c = 0; c < FIN / 4; ++c) {
    float4 t4 = ap[c];
    a[4 * c + 0] = t4.x; a[4 * c + 1] = t4.y; a[4 * c + 2] = t4.z; a[4 * c + 3] = t4.w;
  }
  float di = dinv[r];
  float h[HID];
  #pragma unroll
  for (int j = 0; j < HID; ++j) h[j] = 0.f;
  #pragma unroll
  for (int k = 0; k < DIN; ++k) {
    float v = a[k];
    #pragma unroll
    for (int j = 0; j < HID; ++j) h[j] = fmaf(v, W[k * HID + j], h[j]);
  }
  float s0 = 0.f, s1 = 0.f, s2 = 0.f, s3 = 0.f;
  #pragma unroll
  for (int k = 0; k < HID; k += 4) {
    h[k]     = fmaxf(fmaf(h[k],     di, bb[k]),     0.f); s0 += h[k];
    h[k + 1] = fmaxf(fmaf(h[k + 1], di, bb[k + 1]), 0.f); s1 += h[k + 1];
    h[k + 2] = fmaxf(fmaf(h[k + 2], di, bb[k + 2]), 0.f); s2 += h[k + 2];
    h[k + 3] = fmaxf(fmaf(h[k + 3], di, bb[k + 3]), 0.f); s3 += h[k + 3];
  }
  float mu = ((s0 + s1) + (s2 + s3)) * (1.f / 64.f);
  float q0 = 0.f, q1 = 0.f, q2 = 0.f, q3 = 0.f;
  #pragma unroll
  for (int k = 0; k < HID; k += 4) {
    float d0 = h[k] - mu, d1 = h[k + 1] - mu, d2 = h[k + 2] - mu, d3 = h[k + 3] - mu;
    h[k] = d0; h[k + 1] = d1; h[k + 2] = d2; h[k + 3] = d3;
    q0 = fmaf(d0, d0, q0); q1 = fmaf(d1, d1, q1);
    q2 = fmaf(d2, d2, q2); q3 = fmaf(d3, d3, q3);
  }
  float inv = rsqrtf(((q0 + q1) + (q2 + q3)) * (1.f / 64.f) + 1e-5f);
  float acc[DOUT];
  #pragma unroll
  for (int j = 0; j < DOUT; ++j) acc[j] = 0.f;
  #pragma unroll
  for (int k = 0; k < HID; ++k) {
    float d = h[k];
    #pragma unroll
    for (int j = 0; j < DOUT; ++j) acc[j] = fmaf(d, gL[k * DOUT + j], acc[j]);
  }
  if (act) {
    float4* op = (float4*)(yout + (size_t)row * FOUT);
    #pragma unroll
    for (int c = 0; c < FOUT / 4; ++c) {
      float o[4];
      #pragma unroll
      for (int u = 0; u < 4; ++u) {
        int j = 4 * c + u;
        float t = 0.f;
        if (j < DOUT) {
          t = fmaxf(fmaf(inv, acc[j], cj[j]), 0.f);
          if (SCALE) t *= di;
        }
        o[u] = t;
      }
      op[c] = make_float4(o[0], o[1], o[2], o[3]);
    }
  }
}

__global__ void k_colmax(const float* __restrict__ x, int N, int D, float* __restrict__ out) {
  int j = threadIdx.x;
  if (j >= D) return;
  float m = 0.f;
  for (int r = blockIdx.x; r < N; r += gridDim.x) m = fmaxf(m, x[r * D + j]);
  atomicMax((int*)&out[j], __float_as_int(m));
}

extern "C" void kernel_launch(void* const* d_in, const int* in_sizes, int n_in,
                              void* d_out, int out_size, void* d_ws, size_t ws_size,
                              hipStream_t stream) {
  const float* x = (const float*)d_in[0];
  const int* ei = (const int*)d_in[1];
  int N = in_sizes[0] / 6;
  int E = in_sizes[1] / 2;
  const int* src = ei;
  const int* dst = ei + E;

  const float *W[3], *b[3], *g[3], *be[3], *L[3], *lb[3];
  for (int l = 0; l < 3; ++l) {
    W[l]  = (const float*)d_in[2 + 6 * l + 0];
    b[l]  = (const float*)d_in[2 + 6 * l + 1];
    g[l]  = (const float*)d_in[2 + 6 * l + 2];
    be[l] = (const float*)d_in[2 + 6 * l + 3];
    L[l]  = (const float*)d_in[2 + 6 * l + 4];
    lb[l] = (const float*)d_in[2 + 6 * l + 5];
  }

  char* p = (char*)d_ws;
  auto alloc = [&](size_t bytes) {
    char* r = p;
    p += (bytes + 255) & ~size_t(255);
    return r;
  };
  int* cnt       = (int*)alloc(sizeof(int) * N);
  int* row_start = (int*)alloc(sizeof(int) * (size_t)(N + 1));
  int* cursor    = (int*)alloc(sizeof(int) * N);
  int* csr_src   = (int*)alloc(sizeof(int) * E);
  float* dinv    = (float*)alloc(sizeof(float) * N);
  int* blocksum  = (int*)alloc(sizeof(int) * SCAN_B);
  int* bucket_cur= (int*)alloc(sizeof(int) * NBMAX);
  float* gL1     = (float*)alloc(sizeof(float) * 64 * 12);
  float* cj1     = (float*)alloc(sizeof(float) * 12);
  float* gL2     = (float*)alloc(sizeof(float) * 64 * 24);
  float* cj2     = (float*)alloc(sizeof(float) * 24);
  float* gL3     = (float*)alloc(sizeof(float) * 64 * 48);
  float* cj3     = (float*)alloc(sizeof(float) * 48);
  float* y1      = (float*)alloc(sizeof(float) * (size_t)N * 8);
  float* y2      = (float*)alloc(sizeof(float) * (size_t)N * 16);
  size_t y3_bytes = sizeof(float) * (size_t)N * 32;
  size_t part_bytes = sizeof(uint2) * (size_t)E;
  float* y3      = (float*)alloc(y3_bytes > part_bytes ? y3_bytes : part_bytes);
  float* aggb    = (float*)alloc(sizeof(float) * (size_t)N * 32);
  float* out3    = (float*)alloc(sizeof(float) * (size_t)N * 48);
  uint2* part    = (uint2*)y3;  // setup-phase only; y3 first written by layer-2 fpost

  float* dout = (float*)d_out;

  const int tpb = 256;
  int nb = (N + SCAN_B - 1) / SCAN_B;
  int nbk = (N + (1 << BSHIFT) - 1) >> BSHIFT;
  k_init<<<(N + tpb - 1) / tpb, tpb, 0, stream>>>(cnt, N, dout, out_size);
  k_prep<<<(5460 + tpb - 1) / tpb, tpb, 0, stream>>>(
      g[0], be[0], L[0], lb[0], g[1], be[1], L[1], lb[1], g[2], be[2], L[2], lb[2],
      gL1, cj1, gL2, cj2, gL3, cj3);
  k_count<<<(E / 4 + tpb - 1) / tpb, tpb, 0, stream>>>(dst, E, cnt);
  k_scan1<<<nb, SCAN_B, 0, stream>>>(cnt, N, row_start, blocksum);
  k_scan2<<<1, SCAN_B, 0, stream>>>(blocksum, nb);
  k_scan3<<<(N + tpb - 1) / tpb, tpb, 0, stream>>>(cnt, blocksum, x, N, E,
                                                   row_start, cursor, dinv, bucket_cur, y1);
  k_part<<<(E + EPB - 1) / EPB, 256, 0, stream>>>(src, dst, E, bucket_cur, part);
  k_fill2<<<nbk * SPLIT, 256, 0, stream>>>(part, row_start, N, cursor, csr_src);

  int rb = (N + 3) / 4;      // k_agg: 4 node-waves per 256-thread block
  int rb64 = (N + 63) / 64;  // k_fpost: 64 rows per 64-thread block

  // layer 1: y1[N,8] -> agg -> fpost -> y2[N,16] (pre-scaled by dinv)
  k_agg<8, 3, 2><<<rb, 256, 0, stream>>>(y1, row_start, csr_src, aggb, N);
  k_fpost<6, 12, 8, 16, true><<<rb64, 64, 0, stream>>>(aggb, dinv, W[0], b[0], gL1, cj1, y2, N);

  // layer 2: y2 -> agg -> fpost -> y3[N,32] (pre-scaled)
  k_agg<16, 4, 4><<<rb, 256, 0, stream>>>(y2, row_start, csr_src, aggb, N);
  k_fpost<12, 24, 16, 32, true><<<rb64, 64, 0, stream>>>(aggb, dinv, W[1], b[1], gL2, cj2, y3, N);

  // layer 3: y3 -> agg -> fpost -> out3[N,48] (raw)
  k_agg<32, 5, 8><<<rb, 256, 0, stream>>>(y3, row_start, csr_src, aggb, N);
  k_fpost<24, 48, 32, 48, false><<<rb64, 64, 0, stream>>>(aggb, dinv, W[2], b[2], gL3, cj3, out3, N);

  k_colmax<<<1024, 64, 0, stream>>>(out3, N, 48, dout);
}

// Round 8
// 369.804 us; speedup vs baseline: 3.0880x; 1.2688x over previous
//
#include <hip/hip_runtime.h>

constexpr int HID = 64;
constexpr int BSHIFT = 9;            // bucket = dst >> 9 (512 nodes per bucket)
constexpr int BSIZE = 1 << BSHIFT;   // 512
constexpr int NBMAX = 256;           // max buckets (N=100k -> 196)
constexpr int EPB = 4096;            // edges per k_part block

__global__ void k_init(float* __restrict__ out, int d, int* __restrict__ bsize, int nb) {
  int i = blockIdx.x * blockDim.x + threadIdx.x;
  if (i < d) out[i] = 0.f;
  if (i < nb) bsize[i] = 0;
}

// Bucket histogram: LDS-aggregated, ~grid*196 global atomics total (vs 1.6M per-node).
__global__ __launch_bounds__(256)
void k_hist(const int* __restrict__ dst, int E, int* __restrict__ bsize) {
  __shared__ int l[NBMAX];
  int t = threadIdx.x;
  for (int i = t; i < NBMAX; i += 256) l[i] = 0;
  __syncthreads();
  int nq = E >> 2;
  const int4* d4 = (const int4*)dst;
  for (int q = blockIdx.x * 256 + t; q < nq; q += gridDim.x * 256) {
    int4 d = d4[q];
    atomicAdd(&l[d.x >> BSHIFT], 1);
    atomicAdd(&l[d.y >> BSHIFT], 1);
    atomicAdd(&l[d.z >> BSHIFT], 1);
    atomicAdd(&l[d.w >> BSHIFT], 1);
  }
  if (blockIdx.x == 0) {
    for (int e = (nq << 2) + t; e < E; e += 256) atomicAdd(&l[dst[e] >> BSHIFT], 1);
  }
  __syncthreads();
  for (int i = t; i < NBMAX; i += 256) if (l[i]) atomicAdd(&bsize[i], l[i]);
}

// Scan 196 bucket sizes -> bucket_base / bucket_cur; sentinels.
__global__ __launch_bounds__(256)
void k_bscan(const int* __restrict__ bsize, int nbk, int E, int N,
             int* __restrict__ bucket_base, int* __restrict__ bucket_cur,
             int* __restrict__ row_start) {
  __shared__ int sm[256];
  int t = threadIdx.x;
  int v = (t < nbk) ? bsize[t] : 0;
  sm[t] = v;
  __syncthreads();
  for (int off = 1; off < 256; off <<= 1) {
    int u = (t >= off) ? sm[t - off] : 0;
    __syncthreads();
    sm[t] += u;
    __syncthreads();
  }
  if (t < nbk) {
    int base = sm[t] - v;
    bucket_base[t] = base;
    bucket_cur[t] = base;
  }
  if (t == 0) { bucket_base[nbk] = E; row_start[N] = E; }
}

// Partition edges into dst-buckets; entry packed as (src<<9)|(dst&511) -> 4B.
__global__ __launch_bounds__(256)
void k_part(const int* __restrict__ src, const int* __restrict__ dst, int E,
            int* __restrict__ bucket_cur, unsigned* __restrict__ part) {
  __shared__ int lcnt[NBMAX];
  __shared__ int lcur[NBMAX];
  int t = threadIdx.x;
  int base = blockIdx.x * EPB;
  for (int i = t; i < NBMAX; i += 256) lcnt[i] = 0;
  __syncthreads();
  bool full = (base + EPB) <= E;
  int4 sv[4], dv[4];
  if (full) {
    const int4* src4 = (const int4*)src;
    const int4* dst4 = (const int4*)dst;
    #pragma unroll
    for (int u = 0; u < 4; ++u) {
      int q = (base >> 2) + u * 256 + t;
      sv[u] = src4[q];
      dv[u] = dst4[q];
    }
    #pragma unroll
    for (int u = 0; u < 4; ++u) {
      atomicAdd(&lcnt[dv[u].x >> BSHIFT], 1);
      atomicAdd(&lcnt[dv[u].y >> BSHIFT], 1);
      atomicAdd(&lcnt[dv[u].z >> BSHIFT], 1);
      atomicAdd(&lcnt[dv[u].w >> BSHIFT], 1);
    }
  } else {
    for (int u = 0; u < 16; ++u) {
      int e = base + u * 256 + t;
      if (e < E) atomicAdd(&lcnt[dst[e] >> BSHIFT], 1);
    }
  }
  __syncthreads();
  for (int i = t; i < NBMAX; i += 256)
    lcur[i] = lcnt[i] ? atomicAdd(&bucket_cur[i], lcnt[i]) : 0;
  __syncthreads();
  if (full) {
    #pragma unroll
    for (int u = 0; u < 4; ++u) {
      int pos;
      pos = atomicAdd(&lcur[dv[u].x >> BSHIFT], 1);
      part[pos] = ((unsigned)sv[u].x << BSHIFT) | ((unsigned)dv[u].x & (BSIZE - 1));
      pos = atomicAdd(&lcur[dv[u].y >> BSHIFT], 1);
      part[pos] = ((unsigned)sv[u].y << BSHIFT) | ((unsigned)dv[u].y & (BSIZE - 1));
      pos = atomicAdd(&lcur[dv[u].z >> BSHIFT], 1);
      part[pos] = ((unsigned)sv[u].z << BSHIFT) | ((unsigned)dv[u].z & (BSIZE - 1));
      pos = atomicAdd(&lcur[dv[u].w >> BSHIFT], 1);
      part[pos] = ((unsigned)sv[u].w << BSHIFT) | ((unsigned)dv[u].w & (BSIZE - 1));
    }
  } else {
    for (int u = 0; u < 16; ++u) {
      int e = base + u * 256 + t;
      if (e < E) {
        int s = src[e], d = dst[e];
        int pos = atomicAdd(&lcur[d >> BSHIFT], 1);
        part[pos] = ((unsigned)s << BSHIFT) | ((unsigned)d & (BSIZE - 1));
      }
    }
  }
}

// Per-bucket: LDS per-node histogram + LDS scan -> row_start/dinv/y1, then
// LDS-cursor scatter -> csr_src. Zero per-node GLOBAL atomics.
__global__ __launch_bounds__(512)
void k_bucket(const unsigned* __restrict__ part, const int* __restrict__ bucket_base,
              const float* __restrict__ x, int N,
              int* __restrict__ row_start, float* __restrict__ dinv,
              float* __restrict__ y1, int* __restrict__ csr_src) {
  __shared__ int hist[BSIZE];
  __shared__ int cur[BSIZE];
  int b = blockIdx.x;
  int t = threadIdx.x;
  int base = bucket_base[b];
  int end = bucket_base[b + 1];
  hist[t] = 0;
  __syncthreads();
  for (int e = base + t; e < end; e += BSIZE)
    atomicAdd(&hist[part[e] & (BSIZE - 1)], 1);
  __syncthreads();
  int c = hist[t];
  for (int off = 1; off < BSIZE; off <<= 1) {
    int u = (t >= off) ? hist[t - off] : 0;
    __syncthreads();
    hist[t] += u;
    __syncthreads();
  }
  int gpos = base + hist[t] - c;  // exclusive prefix + bucket base
  cur[t] = gpos;
  int node = (b << BSHIFT) + t;
  if (node < N) {
    row_start[node] = gpos;
    float di = rsqrtf((float)(c + 1));
    dinv[node] = di;
    const float* xr = x + (size_t)node * 6;
    float4* yp = (float4*)(y1 + (size_t)node * 8);
    yp[0] = make_float4(xr[0] * di, xr[1] * di, xr[2] * di, xr[3] * di);
    yp[1] = make_float4(xr[4] * di, xr[5] * di, 0.f, 0.f);
  }
  __syncthreads();
  for (int e = base + t; e < end; e += BSIZE) {
    unsigned u = part[e];
    int pos = atomicAdd(&cur[u & (BSIZE - 1)], 1);
    csr_src[pos] = (int)(u >> BSHIFT);
  }
}

// Precompute gL[k][j] = g[k]*L[k][j] and cj[j] = lb[j] + sum_k be[k]*L[k][j].
__global__ void k_prep(const float* __restrict__ g1, const float* __restrict__ be1,
                       const float* __restrict__ L1, const float* __restrict__ lb1,
                       const float* __restrict__ g2, const float* __restrict__ be2,
                       const float* __restrict__ L2, const float* __restrict__ lb2,
                       const float* __restrict__ g3, const float* __restrict__ be3,
                       const float* __restrict__ L3, const float* __restrict__ lb3,
                       float* __restrict__ gL1, float* __restrict__ cj1,
                       float* __restrict__ gL2, float* __restrict__ cj2,
                       float* __restrict__ gL3, float* __restrict__ cj3) {
  int t = blockIdx.x * blockDim.x + threadIdx.x;
  if (t < 768) gL1[t] = g1[t / 12] * L1[t];
  else if (t < 768 + 1536) { int i = t - 768;  gL2[i] = g2[i / 24] * L2[i]; }
  else if (t < 2304 + 3072) { int i = t - 2304; gL3[i] = g3[i / 48] * L3[i]; }
  else if (t < 5376 + 84) {
    int i = t - 5376;
    if (i < 12) {
      float s = lb1[i];
      for (int k = 0; k < HID; ++k) s += be1[k] * L1[k * 12 + i];
      cj1[i] = s;
    } else if (i < 36) {
      int j = i - 12;
      float s = lb2[j];
      for (int k = 0; k < HID; ++k) s += be2[k] * L2[k * 24 + j];
      cj2[j] = s;
    } else {
      int j = i - 36;
      float s = lb3[j];
      for (int k = 0; k < HID; ++k) s += be3[k] * L3[k * 48 + j];
      cj3[j] = s;
    }
  }
}

// Gather-aggregate of pre-scaled features y [N][F] (F=8/16/32 padded).
// U*C = 16 edges issued per iteration; typical (deg~16) row = one round.
template<int F, int LOGF, int U>
__global__ __launch_bounds__(256)
void k_agg(const float* __restrict__ y, const int* __restrict__ row_start,
           const int* __restrict__ csr, float* __restrict__ agg, int N) {
  constexpr int C = 64 / F;
  int wid = (blockIdx.x * blockDim.x + threadIdx.x) >> 6;
  if (wid >= N) return;
  int lane = threadIdx.x & 63;
  int es = lane >> LOGF;
  int f = lane & (F - 1);
  int e0 = row_start[wid], e1 = row_start[wid + 1];
  float acc = 0.f;
  for (int e = e0 + es; e < e1; e += U * C) {
    float v[U];
    #pragma unroll
    for (int u = 0; u < U; ++u) {
      int ee = e + u * C;
      int ec = min(ee, e1 - 1);
      int s = csr[ec];
      float val = y[(size_t)s * F + f];
      v[u] = (ee < e1) ? val : 0.f;
    }
    #pragma unroll
    for (int u = 0; u < U; ++u) acc += v[u];
  }
  #pragma unroll
  for (int m = F; m < 64; m <<= 1) acc += __shfl_xor(acc, m);
  if (lane < F) {
    acc += y[(size_t)wid * F + f];  // self loop (y already *dinv[self])
    agg[(size_t)wid * F + f] = acc;
  }
}

// Fused per-row epilogue: h = relu(dinv*(agg@W) + b); LN in-register;
// out = relu(inv*(d@gL) + cj); optionally pre-scale by dinv for next gather.
template<int DIN, int DOUT, int FIN, int FOUT, bool SCALE>
__global__ __launch_bounds__(64)
void k_fpost(const float* __restrict__ agg, const float* __restrict__ dinv,
             const float* __restrict__ W, const float* __restrict__ bb,
             const float* __restrict__ gL, const float* __restrict__ cj,
             float* __restrict__ yout, int N) {
  int row = blockIdx.x * 64 + threadIdx.x;
  bool act = row < N;
  int r = act ? row : N - 1;
  float a[FIN];
  const float4* ap = (const float4*)(agg + (size_t)r * FIN);
  #pragma unroll
  for (int c = 0; c < FIN / 4; ++c) {
    float4 t4 = ap[c];
    a[4 * c + 0] = t4.x; a[4 * c + 1] = t4.y; a[4 * c + 2] = t4.z; a[4 * c + 3] = t4.w;
  }
  float di = dinv[r];
  float h[HID];
  #pragma unroll
  for (int j = 0; j < HID; ++j) h[j] = 0.f;
  #pragma unroll
  for (int k = 0; k < DIN; ++k) {
    float v = a[k];
    #pragma unroll
    for (int j = 0; j < HID; ++j) h[j] = fmaf(v, W[k * HID + j], h[j]);
  }
  float s0 = 0.f, s1 = 0.f, s2 = 0.f, s3 = 0.f;
  #pragma unroll
  for (int k = 0; k < HID; k += 4) {
    h[k]     = fmaxf(fmaf(h[k],     di, bb[k]),     0.f); s0 += h[k];
    h[k + 1] = fmaxf(fmaf(h[k + 1], di, bb[k + 1]), 0.f); s1 += h[k + 1];
    h[k + 2] = fmaxf(fmaf(h[k + 2], di, bb[k + 2]), 0.f); s2 += h[k + 2];
    h[k + 3] = fmaxf(fmaf(h[k + 3], di, bb[k + 3]), 0.f); s3 += h[k + 3];
  }
  float mu = ((s0 + s1) + (s2 + s3)) * (1.f / 64.f);
  float q0 = 0.f, q1 = 0.f, q2 = 0.f, q3 = 0.f;
  #pragma unroll
  for (int k = 0; k < HID; k += 4) {
    float d0 = h[k] - mu, d1 = h[k + 1] - mu, d2 = h[k + 2] - mu, d3 = h[k + 3] - mu;
    h[k] = d0; h[k + 1] = d1; h[k + 2] = d2; h[k + 3] = d3;
    q0 = fmaf(d0, d0, q0); q1 = fmaf(d1, d1, q1);
    q2 = fmaf(d2, d2, q2); q3 = fmaf(d3, d3, q3);
  }
  float inv = rsqrtf(((q0 + q1) + (q2 + q3)) * (1.f / 64.f) + 1e-5f);
  float acc[DOUT];
  #pragma unroll
  for (int j = 0; j < DOUT; ++j) acc[j] = 0.f;
  #pragma unroll
  for (int k = 0; k < HID; ++k) {
    float d = h[k];
    #pragma unroll
    for (int j = 0; j < DOUT; ++j) acc[j] = fmaf(d, gL[k * DOUT + j], acc[j]);
  }
  if (act) {
    float4* op = (float4*)(yout + (size_t)row * FOUT);
    #pragma unroll
    for (int c = 0; c < FOUT / 4; ++c) {
      float o[4];
      #pragma unroll
      for (int u = 0; u < 4; ++u) {
        int j = 4 * c + u;
        float t = 0.f;
        if (j < DOUT) {
          t = fmaxf(fmaf(inv, acc[j], cj[j]), 0.f);
          if (SCALE) t *= di;
        }
        o[u] = t;
      }
      op[c] = make_float4(o[0], o[1], o[2], o[3]);
    }
  }
}

__global__ void k_colmax(const float* __restrict__ x, int N, int D, float* __restrict__ out) {
  int j = threadIdx.x;
  if (j >= D) return;
  float m = 0.f;
  for (int r = blockIdx.x; r < N; r += gridDim.x) m = fmaxf(m, x[r * D + j]);
  atomicMax((int*)&out[j], __float_as_int(m));
}

extern "C" void kernel_launch(void* const* d_in, const int* in_sizes, int n_in,
                              void* d_out, int out_size, void* d_ws, size_t ws_size,
                              hipStream_t stream) {
  const float* x = (const float*)d_in[0];
  const int* ei = (const int*)d_in[1];
  int N = in_sizes[0] / 6;
  int E = in_sizes[1] / 2;
  const int* src = ei;
  const int* dst = ei + E;

  const float *W[3], *b[3], *g[3], *be[3], *L[3], *lb[3];
  for (int l = 0; l < 3; ++l) {
    W[l]  = (const float*)d_in[2 + 6 * l + 0];
    b[l]  = (const float*)d_in[2 + 6 * l + 1];
    g[l]  = (const float*)d_in[2 + 6 * l + 2];
    be[l] = (const float*)d_in[2 + 6 * l + 3];
    L[l]  = (const float*)d_in[2 + 6 * l + 4];
    lb[l] = (const float*)d_in[2 + 6 * l + 5];
  }

  char* p = (char*)d_ws;
  auto alloc = [&](size_t bytes) {
    char* r = p;
    p += (bytes + 255) & ~size_t(255);
    return r;
  };
  int* row_start   = (int*)alloc(sizeof(int) * (size_t)(N + 1));
  int* csr_src     = (int*)alloc(sizeof(int) * E);
  float* dinv      = (float*)alloc(sizeof(float) * N);
  int* bsize       = (int*)alloc(sizeof(int) * NBMAX);
  int* bucket_base = (int*)alloc(sizeof(int) * (NBMAX + 1));
  int* bucket_cur  = (int*)alloc(sizeof(int) * NBMAX);
  float* gL1     = (float*)alloc(sizeof(float) * 64 * 12);
  float* cj1     = (float*)alloc(sizeof(float) * 12);
  float* gL2     = (float*)alloc(sizeof(float) * 64 * 24);
  float* cj2     = (float*)alloc(sizeof(float) * 24);
  float* gL3     = (float*)alloc(sizeof(float) * 64 * 48);
  float* cj3     = (float*)alloc(sizeof(float) * 48);
  float* y1      = (float*)alloc(sizeof(float) * (size_t)N * 8);
  float* y2      = (float*)alloc(sizeof(float) * (size_t)N * 16);
  size_t y3_bytes = sizeof(float) * (size_t)N * 32;
  size_t part_bytes = sizeof(unsigned) * (size_t)E;
  float* y3      = (float*)alloc(y3_bytes > part_bytes ? y3_bytes : part_bytes);
  float* aggb    = (float*)alloc(sizeof(float) * (size_t)N * 32);
  float* out3    = (float*)alloc(sizeof(float) * (size_t)N * 48);
  unsigned* part = (unsigned*)y3;  // setup-phase only; y3 first written by layer-2 fpost

  float* dout = (float*)d_out;

  const int tpb = 256;
  int nbk = (N + BSIZE - 1) >> BSHIFT;  // 196 buckets

  k_init<<<1, 256, 0, stream>>>(dout, out_size, bsize, nbk);
  k_prep<<<(5460 + tpb - 1) / tpb, tpb, 0, stream>>>(
      g[0], be[0], L[0], lb[0], g[1], be[1], L[1], lb[1], g[2], be[2], L[2], lb[2],
      gL1, cj1, gL2, cj2, gL3, cj3);
  k_hist<<<200, 256, 0, stream>>>(dst, E, bsize);
  k_bscan<<<1, 256, 0, stream>>>(bsize, nbk, E, N, bucket_base, bucket_cur, row_start);
  k_part<<<(E + EPB - 1) / EPB, 256, 0, stream>>>(src, dst, E, bucket_cur, part);
  k_bucket<<<nbk, BSIZE, 0, stream>>>(part, bucket_base, x, N, row_start, dinv, y1, csr_src);

  int rb = (N + 3) / 4;      // k_agg: 4 node-waves per 256-thread block
  int rb64 = (N + 63) / 64;  // k_fpost: 64 rows per 64-thread block

  // layer 1: y1[N,8] -> agg -> fpost -> y2[N,16] (pre-scaled by dinv)
  k_agg<8, 3, 2><<<rb, 256, 0, stream>>>(y1, row_start, csr_src, aggb, N);
  k_fpost<6, 12, 8, 16, true><<<rb64, 64, 0, stream>>>(aggb, dinv, W[0], b[0], gL1, cj1, y2, N);

  // layer 2: y2 -> agg -> fpost -> y3[N,32] (pre-scaled)
  k_agg<16, 4, 4><<<rb, 256, 0, stream>>>(y2, row_start, csr_src, aggb, N);
  k_fpost<12, 24, 16, 32, true><<<rb64, 64, 0, stream>>>(aggb, dinv, W[1], b[1], gL2, cj2, y3, N);

  // layer 3: y3 -> agg -> fpost -> out3[N,48] (raw)
  k_agg<32, 5, 8><<<rb, 256, 0, stream>>>(y3, row_start, csr_src, aggb, N);
  k_fpost<24, 48, 32, 48, false><<<rb64, 64, 0, stream>>>(aggb, dinv, W[2], b[2], gL3, cj3, out3, N);

  k_colmax<<<1024, 64, 0, stream>>>(out3, N, 48, dout);
}

// Round 9
// 345.425 us; speedup vs baseline: 3.3059x; 1.0706x over previous
//
#include <hip/hip_runtime.h>

constexpr int HID = 64;
constexpr int BSHIFT = 9;            // bucket = dst >> 9 (512 nodes per bucket)
constexpr int BSIZE = 1 << BSHIFT;   // 512
constexpr int NBMAX = 256;           // max buckets (N=100k -> 196)
constexpr int EPB = 4096;            // edges per k_part block

// Merged init + weight-prep: gL[k][j] = g[k]*L[k][j]; cj[j] = lb[j] + sum_k be[k]*L[k][j].
__global__ void k_init_prep(float* __restrict__ out, int d, int* __restrict__ bsize, int nb,
                            const float* __restrict__ g1, const float* __restrict__ be1,
                            const float* __restrict__ L1, const float* __restrict__ lb1,
                            const float* __restrict__ g2, const float* __restrict__ be2,
                            const float* __restrict__ L2, const float* __restrict__ lb2,
                            const float* __restrict__ g3, const float* __restrict__ be3,
                            const float* __restrict__ L3, const float* __restrict__ lb3,
                            float* __restrict__ gL1, float* __restrict__ cj1,
                            float* __restrict__ gL2, float* __restrict__ cj2,
                            float* __restrict__ gL3, float* __restrict__ cj3) {
  int t = blockIdx.x * blockDim.x + threadIdx.x;
  if (t < d) out[t] = 0.f;
  if (t < nb) bsize[t] = 0;
  if (t < 768) gL1[t] = g1[t / 12] * L1[t];
  else if (t < 768 + 1536) { int i = t - 768;  gL2[i] = g2[i / 24] * L2[i]; }
  else if (t < 2304 + 3072) { int i = t - 2304; gL3[i] = g3[i / 48] * L3[i]; }
  else if (t < 5376 + 84) {
    int i = t - 5376;
    if (i < 12) {
      float s = lb1[i];
      for (int k = 0; k < HID; ++k) s += be1[k] * L1[k * 12 + i];
      cj1[i] = s;
    } else if (i < 36) {
      int j = i - 12;
      float s = lb2[j];
      for (int k = 0; k < HID; ++k) s += be2[k] * L2[k * 24 + j];
      cj2[j] = s;
    } else {
      int j = i - 36;
      float s = lb3[j];
      for (int k = 0; k < HID; ++k) s += be3[k] * L3[k * 48 + j];
      cj3[j] = s;
    }
  }
}

// Bucket histogram: LDS-aggregated, ~grid*196 global atomics total.
__global__ __launch_bounds__(256)
void k_hist(const int* __restrict__ dst, int E, int* __restrict__ bsize) {
  __shared__ int l[NBMAX];
  int t = threadIdx.x;
  for (int i = t; i < NBMAX; i += 256) l[i] = 0;
  __syncthreads();
  int nq = E >> 2;
  const int4* d4 = (const int4*)dst;
  for (int q = blockIdx.x * 256 + t; q < nq; q += gridDim.x * 256) {
    int4 d = d4[q];
    atomicAdd(&l[d.x >> BSHIFT], 1);
    atomicAdd(&l[d.y >> BSHIFT], 1);
    atomicAdd(&l[d.z >> BSHIFT], 1);
    atomicAdd(&l[d.w >> BSHIFT], 1);
  }
  if (blockIdx.x == 0) {
    for (int e = (nq << 2) + t; e < E; e += 256) atomicAdd(&l[dst[e] >> BSHIFT], 1);
  }
  __syncthreads();
  for (int i = t; i < NBMAX; i += 256) if (l[i]) atomicAdd(&bsize[i], l[i]);
}

// Scan 196 bucket sizes -> bucket_base / bucket_cur; sentinels.
__global__ __launch_bounds__(256)
void k_bscan(const int* __restrict__ bsize, int nbk, int E, int N,
             int* __restrict__ bucket_base, int* __restrict__ bucket_cur,
             int* __restrict__ row_start) {
  __shared__ int sm[256];
  int t = threadIdx.x;
  int v = (t < nbk) ? bsize[t] : 0;
  sm[t] = v;
  __syncthreads();
  for (int off = 1; off < 256; off <<= 1) {
    int u = (t >= off) ? sm[t - off] : 0;
    __syncthreads();
    sm[t] += u;
    __syncthreads();
  }
  if (t < nbk) {
    int base = sm[t] - v;
    bucket_base[t] = base;
    bucket_cur[t] = base;
  }
  if (t == 0) { bucket_base[nbk] = E; row_start[N] = E; }
}

// Partition edges into dst-buckets; entry packed as (src<<9)|(dst&511) -> 4B.
__global__ __launch_bounds__(256)
void k_part(const int* __restrict__ src, const int* __restrict__ dst, int E,
            int* __restrict__ bucket_cur, unsigned* __restrict__ part) {
  __shared__ int lcnt[NBMAX];
  __shared__ int lcur[NBMAX];
  int t = threadIdx.x;
  int base = blockIdx.x * EPB;
  for (int i = t; i < NBMAX; i += 256) lcnt[i] = 0;
  __syncthreads();
  bool full = (base + EPB) <= E;
  int4 sv[4], dv[4];
  if (full) {
    const int4* src4 = (const int4*)src;
    const int4* dst4 = (const int4*)dst;
    #pragma unroll
    for (int u = 0; u < 4; ++u) {
      int q = (base >> 2) + u * 256 + t;
      sv[u] = src4[q];
      dv[u] = dst4[q];
    }
    #pragma unroll
    for (int u = 0; u < 4; ++u) {
      atomicAdd(&lcnt[dv[u].x >> BSHIFT], 1);
      atomicAdd(&lcnt[dv[u].y >> BSHIFT], 1);
      atomicAdd(&lcnt[dv[u].z >> BSHIFT], 1);
      atomicAdd(&lcnt[dv[u].w >> BSHIFT], 1);
    }
  } else {
    for (int u = 0; u < 16; ++u) {
      int e = base + u * 256 + t;
      if (e < E) atomicAdd(&lcnt[dst[e] >> BSHIFT], 1);
    }
  }
  __syncthreads();
  for (int i = t; i < NBMAX; i += 256)
    lcur[i] = lcnt[i] ? atomicAdd(&bucket_cur[i], lcnt[i]) : 0;
  __syncthreads();
  if (full) {
    #pragma unroll
    for (int u = 0; u < 4; ++u) {
      int pos;
      pos = atomicAdd(&lcur[dv[u].x >> BSHIFT], 1);
      part[pos] = ((unsigned)sv[u].x << BSHIFT) | ((unsigned)dv[u].x & (BSIZE - 1));
      pos = atomicAdd(&lcur[dv[u].y >> BSHIFT], 1);
      part[pos] = ((unsigned)sv[u].y << BSHIFT) | ((unsigned)dv[u].y & (BSIZE - 1));
      pos = atomicAdd(&lcur[dv[u].z >> BSHIFT], 1);
      part[pos] = ((unsigned)sv[u].z << BSHIFT) | ((unsigned)dv[u].z & (BSIZE - 1));
      pos = atomicAdd(&lcur[dv[u].w >> BSHIFT], 1);
      part[pos] = ((unsigned)sv[u].w << BSHIFT) | ((unsigned)dv[u].w & (BSIZE - 1));
    }
  } else {
    for (int u = 0; u < 16; ++u) {
      int e = base + u * 256 + t;
      if (e < E) {
        int s = src[e], d = dst[e];
        int pos = atomicAdd(&lcur[d >> BSHIFT], 1);
        part[pos] = ((unsigned)s << BSHIFT) | ((unsigned)d & (BSIZE - 1));
      }
    }
  }
}

// Per-bucket: LDS per-node histogram + LDS scan -> row_start/dinv/y1, then
// LDS-cursor scatter -> csr_src. Zero per-node GLOBAL atomics.
__global__ __launch_bounds__(512)
void k_bucket(const unsigned* __restrict__ part, const int* __restrict__ bucket_base,
              const float* __restrict__ x, int N,
              int* __restrict__ row_start, float* __restrict__ dinv,
              float* __restrict__ y1, int* __restrict__ csr_src) {
  __shared__ int hist[BSIZE];
  __shared__ int cur[BSIZE];
  int b = blockIdx.x;
  int t = threadIdx.x;
  int base = bucket_base[b];
  int end = bucket_base[b + 1];
  hist[t] = 0;
  __syncthreads();
  for (int e = base + t; e < end; e += BSIZE)
    atomicAdd(&hist[part[e] & (BSIZE - 1)], 1);
  __syncthreads();
  int c = hist[t];
  for (int off = 1; off < BSIZE; off <<= 1) {
    int u = (t >= off) ? hist[t - off] : 0;
    __syncthreads();
    hist[t] += u;
    __syncthreads();
  }
  int gpos = base + hist[t] - c;  // exclusive prefix + bucket base
  cur[t] = gpos;
  int node = (b << BSHIFT) + t;
  if (node < N) {
    row_start[node] = gpos;
    float di = rsqrtf((float)(c + 1));
    dinv[node] = di;
    const float* xr = x + (size_t)node * 6;
    float4* yp = (float4*)(y1 + (size_t)node * 8);
    yp[0] = make_float4(xr[0] * di, xr[1] * di, xr[2] * di, xr[3] * di);
    yp[1] = make_float4(xr[4] * di, xr[5] * di, 0.f, 0.f);
  }
  __syncthreads();
  for (int e = base + t; e < end; e += BSIZE) {
    unsigned u = part[e];
    int pos = atomicAdd(&cur[u & (BSIZE - 1)], 1);
    csr_src[pos] = (int)(u >> BSHIFT);
  }
}

// Gather-aggregate of pre-scaled features y [N][F] (F=8/16/32 padded).
// U*C = 32 edges issued per round -> deg<=32 rows (>99.9%) finish in ONE
// latency round. Clamped tail loads hit the same cache line (same s, f).
template<int F, int LOGF, int U>
__global__ __launch_bounds__(256)
void k_agg(const float* __restrict__ y, const int* __restrict__ row_start,
           const int* __restrict__ csr, float* __restrict__ agg, int N) {
  constexpr int C = 64 / F;
  int wid = (blockIdx.x * blockDim.x + threadIdx.x) >> 6;
  if (wid >= N) return;
  int lane = threadIdx.x & 63;
  int es = lane >> LOGF;
  int f = lane & (F - 1);
  int e0 = row_start[wid], e1 = row_start[wid + 1];
  float acc = 0.f;
  for (int e = e0 + es; e < e1; e += U * C) {
    float v[U];
    #pragma unroll
    for (int u = 0; u < U; ++u) {
      int ee = e + u * C;
      int ec = min(ee, e1 - 1);
      int s = csr[ec];
      float val = y[(size_t)s * F + f];
      v[u] = (ee < e1) ? val : 0.f;
    }
    #pragma unroll
    for (int u = 0; u < U; ++u) acc += v[u];
  }
  #pragma unroll
  for (int m = F; m < 64; m <<= 1) acc += __shfl_xor(acc, m);
  if (lane < F) {
    acc += y[(size_t)wid * F + f];  // self loop (y already *dinv[self])
    agg[(size_t)wid * F + f] = acc;
  }
}

// Fused per-row epilogue (layers 1-2): h = relu(dinv*(agg@W) + b); LN in-reg;
// out = relu(inv*(d@gL) + cj) * dinv (pre-scaled for next gather).
template<int DIN, int DOUT, int FIN, int FOUT>
__global__ __launch_bounds__(64)
void k_fpost(const float* __restrict__ agg, const float* __restrict__ dinv,
             const float* __restrict__ W, const float* __restrict__ bb,
             const float* __restrict__ gL, const float* __restrict__ cj,
             float* __restrict__ yout, int N) {
  int row = blockIdx.x * 64 + threadIdx.x;
  bool act = row < N;
  int r = act ? row : N - 1;
  float a[FIN];
  const float4* ap = (const float4*)(agg + (size_t)r * FIN);
  #pragma unroll
  for (int c = 0; c < FIN / 4; ++c) {
    float4 t4 = ap[c];
    a[4 * c + 0] = t4.x; a[4 * c + 1] = t4.y; a[4 * c + 2] = t4.z; a[4 * c + 3] = t4.w;
  }
  float di = dinv[r];
  float h[HID];
  #pragma unroll
  for (int j = 0; j < HID; ++j) h[j] = 0.f;
  #pragma unroll
  for (int k = 0; k < DIN; ++k) {
    float v = a[k];
    #pragma unroll
    for (int j = 0; j < HID; ++j) h[j] = fmaf(v, W[k * HID + j], h[j]);
  }
  float s0 = 0.f, s1 = 0.f, s2 = 0.f, s3 = 0.f;
  #pragma unroll
  for (int k = 0; k < HID; k += 4) {
    h[k]     = fmaxf(fmaf(h[k],     di, bb[k]),     0.f); s0 += h[k];
    h[k + 1] = fmaxf(fmaf(h[k + 1], di, bb[k + 1]), 0.f); s1 += h[k + 1];
    h[k + 2] = fmaxf(fmaf(h[k + 2], di, bb[k + 2]), 0.f); s2 += h[k + 2];
    h[k + 3] = fmaxf(fmaf(h[k + 3], di, bb[k + 3]), 0.f); s3 += h[k + 3];
  }
  float mu = ((s0 + s1) + (s2 + s3)) * (1.f / 64.f);
  float q0 = 0.f, q1 = 0.f, q2 = 0.f, q3 = 0.f;
  #pragma unroll
  for (int k = 0; k < HID; k += 4) {
    float d0 = h[k] - mu, d1 = h[k + 1] - mu, d2 = h[k + 2] - mu, d3 = h[k + 3] - mu;
    h[k] = d0; h[k + 1] = d1; h[k + 2] = d2; h[k + 3] = d3;
    q0 = fmaf(d0, d0, q0); q1 = fmaf(d1, d1, q1);
    q2 = fmaf(d2, d2, q2); q3 = fmaf(d3, d3, q3);
  }
  float inv = rsqrtf(((q0 + q1) + (q2 + q3)) * (1.f / 64.f) + 1e-5f);
  float acc[DOUT];
  #pragma unroll
  for (int j = 0; j < DOUT; ++j) acc[j] = 0.f;
  #pragma unroll
  for (int k = 0; k < HID; ++k) {
    float d = h[k];
    #pragma unroll
    for (int j = 0; j < DOUT; ++j) acc[j] = fmaf(d, gL[k * DOUT + j], acc[j]);
  }
  if (act) {
    float4* op = (float4*)(yout + (size_t)row * FOUT);
    #pragma unroll
    for (int c = 0; c < FOUT / 4; ++c) {
      float o[4];
      #pragma unroll
      for (int u = 0; u < 4; ++u) {
        int j = 4 * c + u;
        o[u] = (j < DOUT) ? fmaxf(fmaf(inv, acc[j], cj[j]), 0.f) * di : 0.f;
      }
      op[c] = make_float4(o[0], o[1], o[2], o[3]);
    }
  }
}

// Layer-3 epilogue fused with global column-max: no out3 materialization.
// Duplicate rows (tail clamp) just re-contribute a real row's values -> max safe.
__global__ __launch_bounds__(256)
void k_fpost3(const float* __restrict__ agg, const float* __restrict__ dinv,
              const float* __restrict__ W, const float* __restrict__ bb,
              const float* __restrict__ gL, const float* __restrict__ cj,
              float* __restrict__ dout, int N) {
  constexpr int DIN = 24, DOUT = 48, FIN = 32;
  __shared__ int lmax[DOUT];
  int t = threadIdx.x;
  int row = blockIdx.x * 256 + t;
  int r = min(row, N - 1);
  float a[FIN];
  const float4* ap = (const float4*)(agg + (size_t)r * FIN);
  #pragma unroll
  for (int c = 0; c < FIN / 4; ++c) {
    float4 t4 = ap[c];
    a[4 * c + 0] = t4.x; a[4 * c + 1] = t4.y; a[4 * c + 2] = t4.z; a[4 * c + 3] = t4.w;
  }
  float di = dinv[r];
  float h[HID];
  #pragma unroll
  for (int j = 0; j < HID; ++j) h[j] = 0.f;
  #pragma unroll
  for (int k = 0; k < DIN; ++k) {
    float v = a[k];
    #pragma unroll
    for (int j = 0; j < HID; ++j) h[j] = fmaf(v, W[k * HID + j], h[j]);
  }
  float s0 = 0.f, s1 = 0.f, s2 = 0.f, s3 = 0.f;
  #pragma unroll
  for (int k = 0; k < HID; k += 4) {
    h[k]     = fmaxf(fmaf(h[k],     di, bb[k]),     0.f); s0 += h[k];
    h[k + 1] = fmaxf(fmaf(h[k + 1], di, bb[k + 1]), 0.f); s1 += h[k + 1];
    h[k + 2] = fmaxf(fmaf(h[k + 2], di, bb[k + 2]), 0.f); s2 += h[k + 2];
    h[k + 3] = fmaxf(fmaf(h[k + 3], di, bb[k + 3]), 0.f); s3 += h[k + 3];
  }
  float mu = ((s0 + s1) + (s2 + s3)) * (1.f / 64.f);
  float q0 = 0.f, q1 = 0.f, q2 = 0.f, q3 = 0.f;
  #pragma unroll
  for (int k = 0; k < HID; k += 4) {
    float d0 = h[k] - mu, d1 = h[k + 1] - mu, d2 = h[k + 2] - mu, d3 = h[k + 3] - mu;
    h[k] = d0; h[k + 1] = d1; h[k + 2] = d2; h[k + 3] = d3;
    q0 = fmaf(d0, d0, q0); q1 = fmaf(d1, d1, q1);
    q2 = fmaf(d2, d2, q2); q3 = fmaf(d3, d3, q3);
  }
  float inv = rsqrtf(((q0 + q1) + (q2 + q3)) * (1.f / 64.f) + 1e-5f);
  float o[DOUT];
  #pragma unroll
  for (int j = 0; j < DOUT; ++j) o[j] = 0.f;
  #pragma unroll
  for (int k = 0; k < HID; ++k) {
    float d = h[k];
    #pragma unroll
    for (int j = 0; j < DOUT; ++j) o[j] = fmaf(d, gL[k * DOUT + j], o[j]);
  }
  #pragma unroll
  for (int j = 0; j < DOUT; ++j) o[j] = fmaxf(fmaf(inv, o[j], cj[j]), 0.f);
  // wave-level elementwise max across 64 lanes
  #pragma unroll
  for (int m = 1; m < 64; m <<= 1) {
    #pragma unroll
    for (int j = 0; j < DOUT; ++j) o[j] = fmaxf(o[j], __shfl_xor(o[j], m));
  }
  if (t < DOUT) lmax[t] = 0;
  __syncthreads();
  if ((t & 63) == 0) {
    #pragma unroll
    for (int j = 0; j < DOUT; ++j) atomicMax(&lmax[j], __float_as_int(o[j]));
  }
  __syncthreads();
  if (t < DOUT) atomicMax((int*)&dout[t], lmax[t]);
}

extern "C" void kernel_launch(void* const* d_in, const int* in_sizes, int n_in,
                              void* d_out, int out_size, void* d_ws, size_t ws_size,
                              hipStream_t stream) {
  const float* x = (const float*)d_in[0];
  const int* ei = (const int*)d_in[1];
  int N = in_sizes[0] / 6;
  int E = in_sizes[1] / 2;
  const int* src = ei;
  const int* dst = ei + E;

  const float *W[3], *b[3], *g[3], *be[3], *L[3], *lb[3];
  for (int l = 0; l < 3; ++l) {
    W[l]  = (const float*)d_in[2 + 6 * l + 0];
    b[l]  = (const float*)d_in[2 + 6 * l + 1];
    g[l]  = (const float*)d_in[2 + 6 * l + 2];
    be[l] = (const float*)d_in[2 + 6 * l + 3];
    L[l]  = (const float*)d_in[2 + 6 * l + 4];
    lb[l] = (const float*)d_in[2 + 6 * l + 5];
  }

  char* p = (char*)d_ws;
  auto alloc = [&](size_t bytes) {
    char* r = p;
    p += (bytes + 255) & ~size_t(255);
    return r;
  };
  int* row_start   = (int*)alloc(sizeof(int) * (size_t)(N + 1));
  int* csr_src     = (int*)alloc(sizeof(int) * E);
  float* dinv      = (float*)alloc(sizeof(float) * N);
  int* bsize       = (int*)alloc(sizeof(int) * NBMAX);
  int* bucket_base = (int*)alloc(sizeof(int) * (NBMAX + 1));
  int* bucket_cur  = (int*)alloc(sizeof(int) * NBMAX);
  float* gL1     = (float*)alloc(sizeof(float) * 64 * 12);
  float* cj1     = (float*)alloc(sizeof(float) * 12);
  float* gL2     = (float*)alloc(sizeof(float) * 64 * 24);
  float* cj2     = (float*)alloc(sizeof(float) * 24);
  float* gL3     = (float*)alloc(sizeof(float) * 64 * 48);
  float* cj3     = (float*)alloc(sizeof(float) * 48);
  float* y1      = (float*)alloc(sizeof(float) * (size_t)N * 8);
  float* y2      = (float*)alloc(sizeof(float) * (size_t)N * 16);
  size_t y3_bytes = sizeof(float) * (size_t)N * 32;
  size_t part_bytes = sizeof(unsigned) * (size_t)E;
  float* y3      = (float*)alloc(y3_bytes > part_bytes ? y3_bytes : part_bytes);
  float* aggb    = (float*)alloc(sizeof(float) * (size_t)N * 32);
  unsigned* part = (unsigned*)y3;  // setup-phase only; y3 first written by layer-2 fpost

  float* dout = (float*)d_out;

  const int tpb = 256;
  int nbk = (N + BSIZE - 1) >> BSHIFT;  // 196 buckets

  k_init_prep<<<(5460 + tpb - 1) / tpb, tpb, 0, stream>>>(
      dout, out_size, bsize, nbk,
      g[0], be[0], L[0], lb[0], g[1], be[1], L[1], lb[1], g[2], be[2], L[2], lb[2],
      gL1, cj1, gL2, cj2, gL3, cj3);
  k_hist<<<200, 256, 0, stream>>>(dst, E, bsize);
  k_bscan<<<1, 256, 0, stream>>>(bsize, nbk, E, N, bucket_base, bucket_cur, row_start);
  k_part<<<(E + EPB - 1) / EPB, 256, 0, stream>>>(src, dst, E, bucket_cur, part);
  k_bucket<<<nbk, BSIZE, 0, stream>>>(part, bucket_base, x, N, row_start, dinv, y1, csr_src);

  int rb = (N + 3) / 4;      // k_agg: 4 node-waves per 256-thread block
  int rb64 = (N + 63) / 64;  // k_fpost: 64 rows per 64-thread block
  int rb256 = (N + 255) / 256;

  // layer 1: y1[N,8] -> agg -> fpost -> y2[N,16] (pre-scaled by dinv)
  k_agg<8, 3, 4><<<rb, 256, 0, stream>>>(y1, row_start, csr_src, aggb, N);
  k_fpost<6, 12, 8, 16><<<rb64, 64, 0, stream>>>(aggb, dinv, W[0], b[0], gL1, cj1, y2, N);

  // layer 2: y2 -> agg -> fpost -> y3[N,32] (pre-scaled)
  k_agg<16, 4, 8><<<rb, 256, 0, stream>>>(y2, row_start, csr_src, aggb, N);
  k_fpost<12, 24, 16, 32><<<rb64, 64, 0, stream>>>(aggb, dinv, W[1], b[1], gL2, cj2, y3, N);

  // layer 3: y3 -> agg -> fused fpost+colmax -> d_out (no out3 materialization)
  k_agg<32, 5, 16><<<rb, 256, 0, stream>>>(y3, row_start, csr_src, aggb, N);
  k_fpost3<<<rb256, 256, 0, stream>>>(aggb, dinv, W[2], b[2], gL3, cj3, dout, N);
}